// Round 10
// baseline (625.530 us; speedup 1.0000x reference)
//
#include <hip/hip_runtime.h>

// ---------------------------------------------------------------------------
// VQ-VAE forward (NCHW). Round 19: conv4 = R17 + register B double-buffer.
//  R18 post-mortem: 8-wave cout-split regressed (76.7->94.5us) even though
//  occupancy doubled (19->40) and FETCH held 32MB -- per-barrier MFMA work
//  halved (24 MFMAs/120cy between 36 block-wide barriers over 8 waves) and
//  per-CU B traffic doubled. Occupancy was not the binding constraint;
//  per-barrier work density was. Reverted to R17's proven shape.
//  Remaining exposure in R17: B loads are just-in-time (~200cy L2 latency on
//  the tap critical path, only 2 waves/SIMD to cover). Fix (T14): prefetch
//  tap s+1's B into registers (nbh/nbl, +32 VGPR) during tap s's 48 MFMAs.
//  VGPR 112->~145 is free: grid caps 2 blocks/CU = 2 waves/SIMD; 145 VGPR
//  still allows 3. No new barriers; B values + MFMA order bit-identical ->
//  absmax 2.441e-4 exact. All other kernels unchanged from R17.
// ---------------------------------------------------------------------------

using short8  = __attribute__((ext_vector_type(8))) short;
using short4v = __attribute__((ext_vector_type(4))) short;
using floatx4 = __attribute__((ext_vector_type(4))) float;

__device__ inline unsigned short bf16rn(float f) {
  unsigned u = __float_as_uint(f);
  unsigned r = (u + 0x7fffu + ((u >> 16) & 1u)) >> 16;
  return (unsigned short)r;
}
__device__ inline float bf2f1(short h) {
  return __uint_as_float(((unsigned)(unsigned short)h) << 16);
}

// ---- deconv tap tables: entry e -> (ky,kx) weight tap
__device__ const int DKY[9]  = {1, 1, 1, 2, 0, 2, 2, 0, 0};
__device__ const int DKX[9]  = {1, 2, 0, 1, 1, 2, 0, 2, 0};

// ---------------- ring zero (split pair) ----------------------------------
__global__ __launch_bounds__(256) void ring_zero(short* __restrict__ h,
                                                 short* __restrict__ l,
                                                 int nimg, int PH, int PW, int C) {
  const int RC = (2 * PW + 2 * (PH - 2)) * C;
  int t = blockIdx.x * 256 + threadIdx.x;
  if (t >= nimg * RC) return;
  const int nl = t / RC;
  int rem = t - nl * RC;
  const int p = rem / C;
  const int ch = rem - p * C;
  int r, c;
  if (p < 2 * PW) {
    r = (p < PW) ? 0 : PH - 1;
    c = (p < PW) ? p : p - PW;
  } else {
    int q = p - 2 * PW;
    if (q < PH - 2) { r = 1 + q; c = 0; }
    else { r = 1 + q - (PH - 2); c = PW - 1; }
  }
  const size_t a = (((size_t)nl * PH + r) * PW + c) * C + ch;
  h[a] = 0; l[a] = 0;
}

// ---------------- ring zero (single buffer) -------------------------------
__global__ __launch_bounds__(256) void ring_zero1(short* __restrict__ h,
                                                  int nimg, int PH, int PW, int C) {
  const int RC = (2 * PW + 2 * (PH - 2)) * C;
  int t = blockIdx.x * 256 + threadIdx.x;
  if (t >= nimg * RC) return;
  const int nl = t / RC;
  int rem = t - nl * RC;
  const int p = rem / C;
  const int ch = rem - p * C;
  int r, c;
  if (p < 2 * PW) {
    r = (p < PW) ? 0 : PH - 1;
    c = (p < PW) ? p : p - PW;
  } else {
    int q = p - 2 * PW;
    if (q < PH - 2) { r = 1 + q; c = 0; }
    else { r = 1 + q - (PH - 2); c = PW - 1; }
  }
  h[(((size_t)nl * PH + r) * PW + c) * C + ch] = 0;
}

// ---------------- conv1: fp32 direct, writes xt [nh][130][130][32] --------
__global__ __launch_bounds__(256) void conv1_xt(const float* __restrict__ x,
                                                const float* __restrict__ w,
                                                const float* __restrict__ bias,
                                                short* __restrict__ oh,
                                                short* __restrict__ ol, int NH) {
  int t = blockIdx.x * 256 + threadIdx.x;
  if (t >= NH * 128 * 128) return;
  const int px = t & 16383;
  const int n  = t >> 14;
  const int r = px >> 7, c = px & 127;
  const int ih0 = 2 * r - 1, iw0 = 2 * c - 1;
  float acc[32];
#pragma unroll
  for (int o = 0; o < 32; ++o) acc[o] = bias[o];
  const float* ip = x + (size_t)n * 2 * 65536;
#pragma unroll
  for (int ic = 0; ic < 2; ++ic, ip += 65536) {
    float v[9];
#pragma unroll
    for (int kh = 0; kh < 3; ++kh) {
      const int ih = ih0 + kh;
#pragma unroll
      for (int kw = 0; kw < 3; ++kw) {
        const int iw = iw0 + kw;
        const bool ok = (ih >= 0) && (ih < 256) && (iw < 256) && (iw >= 0);
        v[kh * 3 + kw] = ok ? ip[ih * 256 + iw] : 0.f;
      }
    }
#pragma unroll
    for (int o = 0; o < 32; ++o) {
      float s = acc[o];
#pragma unroll
      for (int k = 0; k < 9; ++k) s = fmaf(v[k], w[(o * 2 + ic) * 9 + k], s);
      acc[o] = s;
    }
  }
  const size_t base = (((size_t)n * 130 + r + 1) * 130 + (c + 1)) * 32;
  short8 vh[4], vl[4];
#pragma unroll
  for (int g = 0; g < 4; ++g) {
#pragma unroll
    for (int kk = 0; kk < 8; ++kk) {
      const float rv = fmaxf(acc[g * 8 + kk], 0.f);
      const unsigned short hh = bf16rn(rv);
      vh[g][kk] = (short)hh;
      vl[g][kk] = (short)bf16rn(rv - __uint_as_float((unsigned)hh << 16));
    }
    *(short8*)(oh + base + g * 8) = vh[g];
    *(short8*)(ol + base + g * 8) = vl[g];
  }
}

// ---------------- fused weight/table prep (R15) ---------------------------
template<int CIN, int COUT>
__device__ inline void wprep_conv_body(int t, const float* __restrict__ w,
                                       short* __restrict__ hi,
                                       short* __restrict__ lo) {
  constexpr int MT = COUT / 16;
  const int j = t & 7;
  const int lane = (t >> 3) & 63;
  const int g = t >> 9;
  const int mt = g % MT;
  const int s = g / MT;
  const int icb = s / 9, tap = s - icb * 9;
  const int kh = tap / 3, kw = tap - kh * 3;
  const int m = mt * 16 + (lane & 15);
  const int ic = icb * 32 + ((lane >> 4) << 3) + j;
  const float v = w[((m * CIN + ic) * 3 + kh) * 3 + kw];
  const unsigned short h = bf16rn(v);
  hi[t] = (short)h;
  lo[t] = (short)bf16rn(v - __uint_as_float((unsigned)h << 16));
}

template<int CIN, int COUT>
__device__ inline void wprep_dec_body(int t, const float* __restrict__ w,
                                      short* __restrict__ hi) {
  constexpr int MT = COUT / 16, ICB = CIN / 32;
  const int j = t & 7;
  const int lane = (t >> 3) & 63;
  const int g = t >> 9;
  const int mt = g % MT;
  const int u = g / MT;
  const int icb = u % ICB;
  const int e = u / ICB;
  const int ky = DKY[e], kx = DKX[e];
  const int m = mt * 16 + (lane & 15);
  const int ic = icb * 32 + ((lane >> 4) << 3) + j;
  hi[t] = (short)bf16rn(w[((ic * COUT + m) * 3 + ky) * 3 + kx]);
}

__global__ __launch_bounds__(256) void prep_all(
    const float* __restrict__ w2, const float* __restrict__ w3,
    const float* __restrict__ w4, const float* __restrict__ dw1,
    const float* __restrict__ dw2, const float* __restrict__ emb,
    short* __restrict__ a2h, short* __restrict__ a2l,
    short* __restrict__ a3h, short* __restrict__ a3l,
    short* __restrict__ a4h, short* __restrict__ a4l,
    short* __restrict__ ad1h, short* __restrict__ ad2h,
    float* __restrict__ nrm, short* __restrict__ ebh,
    short* __restrict__ ebl) {
  const int bb = blockIdx.x;
  const int tid = threadIdx.x;
  if (bb < 72) {
    wprep_conv_body<32, 64>(bb * 256 + tid, w2, a2h, a2l);
  } else if (bb < 360) {
    wprep_conv_body<64, 128>((bb - 72) * 256 + tid, w3, a3h, a3l);
  } else if (bb < 936) {
    wprep_conv_body<128, 128>((bb - 360) * 256 + tid, w4, a4h, a4l);
  } else if (bb < 1224) {
    wprep_dec_body<128, 64>((bb - 936) * 256 + tid, dw1, ad1h);
  } else if (bb < 1296) {
    wprep_dec_body<64, 32>((bb - 1224) * 256 + tid, dw2, ad2h);
  } else if (bb < 1424) {
    const int t = (bb - 1296) * 256 + tid;   // < 32768
    const int j  = t & 7;
    const int l  = (t >> 3) & 63;
    const int kk = (t >> 9) & 1;
    const int ct = t >> 10;
    const int code = ct * 16 + (l & 15);
    const int k = kk * 32 + ((l >> 4) << 3) + j;
    const float v = emb[code * 64 + k];
    const unsigned short h = bf16rn(v);
    ebh[t] = (short)h;
    ebl[t] = (short)bf16rn(v - __uint_as_float((unsigned)h << 16));
  } else {
    const int jj = (bb - 1424) * 256 + tid;
    if (jj < 512) {
      float s = 0.f;
      const float* e = emb + jj * 64;
#pragma unroll
      for (int k = 0; k < 64; ++k) s = fmaf(e[k], e[k], s);
      nrm[jj] = s;
    }
  }
}

// ------- generic strided conv MFMA (split xt -> split xt), NP tiles -------
// R15: per-tap A-slice LDS staging, double-buffered.
template<int CIN, int COUT, int OH, int OW, int S, int PHI, int PWI, int PHO, int PWO, int NP>
__global__ __launch_bounds__(256) void conv_mfma_xt(
    const short* __restrict__ xih, const short* __restrict__ xil,
    const short* __restrict__ ah,  const short* __restrict__ al,
    const float* __restrict__ bias,
    short* __restrict__ xoh, short* __restrict__ xol) {
  constexpr int MT = COUT / 16, ICB = CIN / 32;
  constexpr int PXB = 64 * NP, TPB = OH * OW / PXB;
  constexpr int NSL = ICB * 9;            // total A slices
  constexpr int CH  = MT * 64;            // short8 chunks per slice (hi or lo)
  constexpr int CPT = (CH + 255) / 256;   // chunks per thread
  __shared__ short ash[2][CH * 8];
  __shared__ short asl2[2][CH * 8];
  const int b = blockIdx.x;
  const int n = b / TPB, pt = b % TPB;
  const int tid = threadIdx.x;
  const int lane = tid & 63, wave = tid >> 6;
  const int quad = lane >> 4;
  int rr[NP], cc[NP];
  size_t bbase[NP];
#pragma unroll
  for (int p = 0; p < NP; ++p) {
    const int pl = pt * PXB + wave * (16 * NP) + p * 16 + (lane & 15);
    rr[p] = pl / OW; cc[p] = pl % OW;
    bbase[p] = (((size_t)n * PHI + S * rr[p]) * PWI + S * cc[p]) * CIN + quad * 8;
  }

  floatx4 acc[MT][NP];
#pragma unroll
  for (int mt = 0; mt < MT; ++mt)
#pragma unroll
    for (int p = 0; p < NP; ++p) acc[mt][p] = (floatx4){0.f, 0.f, 0.f, 0.f};

  const short8* __restrict__ ah8 = (const short8*)ah;
  const short8* __restrict__ al8 = (const short8*)al;

  // prologue: stage A slice 0 into buffer 0
  short8 ra[CPT], rl[CPT];
#pragma unroll
  for (int c = 0; c < CPT; ++c) {
    const int idx = tid + c * 256;
    if (idx < CH) { ra[c] = ah8[idx]; rl[c] = al8[idx]; }
  }
#pragma unroll
  for (int c = 0; c < CPT; ++c) {
    const int idx = tid + c * 256;
    if (idx < CH) {
      *(short8*)(ash[0] + idx * 8) = ra[c];
      *(short8*)(asl2[0] + idx * 8) = rl[c];
    }
  }
  __syncthreads();

  int s = 0;
  for (int icb = 0; icb < ICB; ++icb) {
#pragma unroll
    for (int tap = 0; tap < 9; ++tap, ++s) {
      // prefetch next A slice into regs (hides under MFMAs)
      if (s + 1 < NSL) {
        const int base = (s + 1) * CH;
#pragma unroll
        for (int c = 0; c < CPT; ++c) {
          const int idx = tid + c * 256;
          if (idx < CH) { ra[c] = ah8[base + idx]; rl[c] = al8[base + idx]; }
        }
      }
      const int kh = tap / 3, kw = tap - kh * 3;
      short8 bh[NP], bl[NP];
#pragma unroll
      for (int p = 0; p < NP; ++p) {
        const size_t be = bbase[p] + (size_t)(kh * PWI + kw) * CIN + icb * 32;
        bh[p] = *(const short8*)(xih + be);
        bl[p] = *(const short8*)(xil + be);
      }
      const short8* __restrict__ a8h = (const short8*)ash[s & 1];
      const short8* __restrict__ a8l = (const short8*)asl2[s & 1];
#pragma unroll
      for (int mt = 0; mt < MT; ++mt) {
        const short8 wh = a8h[mt * 64 + lane];
        const short8 wl = a8l[mt * 64 + lane];
#pragma unroll
        for (int p = 0; p < NP; ++p) {
          acc[mt][p] = __builtin_amdgcn_mfma_f32_16x16x32_bf16(wh, bh[p], acc[mt][p], 0, 0, 0);
          acc[mt][p] = __builtin_amdgcn_mfma_f32_16x16x32_bf16(wh, bl[p], acc[mt][p], 0, 0, 0);
          acc[mt][p] = __builtin_amdgcn_mfma_f32_16x16x32_bf16(wl, bh[p], acc[mt][p], 0, 0, 0);
        }
      }
      if (s + 1 < NSL) {
        const int nb = (s + 1) & 1;
#pragma unroll
        for (int c = 0; c < CPT; ++c) {
          const int idx = tid + c * 256;
          if (idx < CH) {
            *(short8*)(ash[nb] + idx * 8) = ra[c];
            *(short8*)(asl2[nb] + idx * 8) = rl[c];
          }
        }
        __syncthreads();
      }
    }
  }
#pragma unroll
  for (int p = 0; p < NP; ++p) {
    const size_t ob = (((size_t)n * PHO + rr[p] + 1) * PWO + (cc[p] + 1)) * COUT + quad * 4;
#pragma unroll
    for (int mt = 0; mt < MT; ++mt) {
      short4v sh, sl;
#pragma unroll
      for (int q = 0; q < 4; ++q) {
        const float v = fmaxf(acc[mt][p][q] + bias[mt * 16 + quad * 4 + q], 0.f);
        const unsigned short hh = bf16rn(v);
        sh[q] = (short)hh;
        sl[q] = (short)bf16rn(v - __uint_as_float((unsigned)hh << 16));
      }
      *(short4v*)(xoh + ob + mt * 16) = sh;
      *(short4v*)(xol + ob + mt * 16) = sl;
    }
  }
}

// ---- fused transposed conv, plain bf16, NP pixel-tiles per wave ----------
// R15: ASTG=1 stages the per-icb A group (9 e-slices) in LDS, double-buffered.
template<int CIN, int COUT, int IH, int IW, int PHI, int PWI, int PHO, int PWO, int NP, int ASTG>
__global__ __launch_bounds__(256) void deconv_bf16_xt(
    const short* __restrict__ xih, const short* __restrict__ ah,
    const float* __restrict__ bias, short* __restrict__ xoh) {
  constexpr int MT = COUT / 16, ICB = CIN / 32;
  constexpr int PXB = 64 * NP, TPB = IH * IW / PXB;
  constexpr int CHI = 9 * MT * 64;               // chunks per icb A-group
  constexpr int CPT = (CHI + 255) / 256;
  constexpr int PHE[9] = {0, 1, 1, 2, 2, 3, 3, 3, 3};
  constexpr int DE[9]  = {0, 0, 1, 0, 2, 0, 1, 2, 3};
  __shared__ short ash[ASTG ? 2 * CHI * 8 : 1];
  const int b = blockIdx.x;
  const int n = b / TPB, pt = b % TPB;
  const int tid = threadIdx.x;
  const int lane = tid & 63, wave = tid >> 6;
  const int quad = lane >> 4;
  int ii[NP], jj[NP];
  size_t p00[NP];
#pragma unroll
  for (int p = 0; p < NP; ++p) {
    const int pl = pt * PXB + wave * (16 * NP) + p * 16 + (lane & 15);
    ii[p] = pl / IW; jj[p] = pl % IW;
    p00[p] = (((size_t)n * PHI + (ii[p] + 1)) * PWI + (jj[p] + 1)) * CIN + quad * 8;
  }

  floatx4 acc[4][MT][NP];
#pragma unroll
  for (int ph = 0; ph < 4; ++ph)
#pragma unroll
    for (int mt = 0; mt < MT; ++mt)
#pragma unroll
      for (int p = 0; p < NP; ++p) acc[ph][mt][p] = (floatx4){0.f, 0.f, 0.f, 0.f};

  const short8* __restrict__ ah8 = (const short8*)ah;

  short8 ra[ASTG ? CPT : 1];
  if constexpr (ASTG) {
    // prologue: stage icb0's 9 e-slices into buffer 0
#pragma unroll
    for (int c = 0; c < CPT; ++c) {
      const int idx = tid + c * 256;
      if (idx < CHI) {
        const int e = idx / (MT * 64);
        const int rem = idx - e * (MT * 64);
        ra[c] = ah8[(e * ICB + 0) * (MT * 64) + rem];
      }
    }
#pragma unroll
    for (int c = 0; c < CPT; ++c) {
      const int idx = tid + c * 256;
      if (idx < CHI) *(short8*)(ash + idx * 8) = ra[c];
    }
    __syncthreads();
  }

  for (int icb = 0; icb < ICB; ++icb) {
    short8 bh[NP][4];
#pragma unroll
    for (int p = 0; p < NP; ++p)
#pragma unroll
      for (int d = 0; d < 4; ++d)
        bh[p][d] = *(const short8*)(xih + p00[p] +
                                    (size_t)((d >> 1) * PWI + (d & 1)) * CIN + icb * 32);
    if constexpr (ASTG) {
      if (icb + 1 < ICB) {
#pragma unroll
        for (int c = 0; c < CPT; ++c) {
          const int idx = tid + c * 256;
          if (idx < CHI) {
            const int e = idx / (MT * 64);
            const int rem = idx - e * (MT * 64);
            ra[c] = ah8[(e * ICB + icb + 1) * (MT * 64) + rem];
          }
        }
      }
    }
#pragma unroll
    for (int e = 0; e < 9; ++e) {
      const int ph = PHE[e], d = DE[e];
#pragma unroll
      for (int mt = 0; mt < MT; ++mt) {
        short8 wh;
        if constexpr (ASTG)
          wh = ((const short8*)(ash + (size_t)(icb & 1) * CHI * 8))[(e * MT + mt) * 64 + lane];
        else
          wh = ah8[((e * ICB + icb) * MT + mt) * 64 + lane];
#pragma unroll
        for (int p = 0; p < NP; ++p)
          acc[ph][mt][p] = __builtin_amdgcn_mfma_f32_16x16x32_bf16(
              wh, bh[p][d], acc[ph][mt][p], 0, 0, 0);
      }
    }
    if constexpr (ASTG) {
      if (icb + 1 < ICB) {
        const size_t nb = (size_t)((icb + 1) & 1) * CHI * 8;
#pragma unroll
        for (int c = 0; c < CPT; ++c) {
          const int idx = tid + c * 256;
          if (idx < CHI) *(short8*)(ash + nb + idx * 8) = ra[c];
        }
        __syncthreads();
      }
    }
  }
#pragma unroll
  for (int p = 0; p < NP; ++p)
#pragma unroll
    for (int ph = 0; ph < 4; ++ph) {
      const int oy = 2 * ii[p] + (ph >> 1), ox = 2 * jj[p] + (ph & 1);
      const size_t ob = (((size_t)n * PHO + oy + 1) * PWO + (ox + 1)) * COUT + quad * 4;
#pragma unroll
      for (int mt = 0; mt < MT; ++mt) {
        short4v sh;
#pragma unroll
        for (int q = 0; q < 4; ++q)
          sh[q] = (short)bf16rn(fmaxf(acc[ph][mt][p][q] + bias[mt * 16 + quad * 4 + q], 0.f));
        *(short4v*)(xoh + ob + mt * 16) = sh;
      }
    }
}

// ---------------- conv4 MFMA (R19): R17 + register B double-buffer --------
// 256 thr, 4 waves, grid N*8, NP=2; A from double-buffered LDS tap-slice;
// B loads for tap s+1 issued during tap s's MFMAs (T14 async split).
__global__ __launch_bounds__(256) void conv4_mfma(
    const short* __restrict__ xthi, const short* __restrict__ xtlo,
    const short* __restrict__ ahi,  const short* __restrict__ alo,
    const float* __restrict__ bias,
    short* __restrict__ ench, short* __restrict__ encl) {
  __shared__ short ash[2][4096];        // 2 x 8192 B  (A hi, one tap slice)
  __shared__ short asl[2][4096];        // 2 x 8192 B  (A lo)
  const int b    = blockIdx.x;          // N*8 blocks, 128 pixels each
  const int n    = b >> 3;
  const int pt   = b & 7;
  const int tid  = threadIdx.x;
  const int lane = tid & 63;
  const int wave = tid >> 6;
  const int kq   = lane >> 4;
  int pl[2];
  size_t bbase[2];
#pragma unroll
  for (int p = 0; p < 2; ++p) {
    pl[p] = pt * 128 + wave * 32 + p * 16 + (lane & 15);
    const int r = pl[p] >> 5, c = pl[p] & 31;
    bbase[p] = (((size_t)n * 34 + r) * 34 + c) * 128 + kq * 8;
  }

  floatx4 acc[8][2];
#pragma unroll
  for (int mt = 0; mt < 8; ++mt)
#pragma unroll
    for (int p = 0; p < 2; ++p) acc[mt][p] = (floatx4){0.f, 0.f, 0.f, 0.f};

  const short8* __restrict__ ah8 = (const short8*)ahi;
  const short8* __restrict__ al8 = (const short8*)alo;

  // A prologue: stage tap-slice 0 into buffer 0
  short8 rah0, rah1, ral0, ral1;
  rah0 = ah8[tid];        rah1 = ah8[tid + 256];
  ral0 = al8[tid];        ral1 = al8[tid + 256];
  *(short8*)(ash[0] + tid * 8) = rah0;
  *(short8*)(ash[0] + (tid + 256) * 8) = rah1;
  *(short8*)(asl[0] + tid * 8) = ral0;
  *(short8*)(asl[0] + (tid + 256) * 8) = ral1;

  // B prologue: load tap 0's B (kh=0,kw=0,icb=0)
  short8 bh[2], bl[2];
#pragma unroll
  for (int p = 0; p < 2; ++p) {
    bh[p] = *(const short8*)(xthi + bbase[p]);
    bl[p] = *(const short8*)(xtlo + bbase[p]);
  }
  __syncthreads();

  int s = 0;
  for (int icb = 0; icb < 4; ++icb) {
#pragma unroll
    for (int tap = 0; tap < 9; ++tap, ++s) {
      // prefetch next A tap-slice into regs
      if (s < 35) {
        const int nb = (s + 1) * 512;
        rah0 = ah8[nb + tid];        rah1 = ah8[nb + tid + 256];
        ral0 = al8[nb + tid];        ral1 = al8[nb + tid + 256];
      }
      // prefetch next tap's B into regs (hides L2 latency under MFMAs)
      short8 nbh[2], nbl[2];
      if (s < 35) {
        const int tapn = (tap == 8) ? 0 : tap + 1;
        const int icbn = (tap == 8) ? icb + 1 : icb;
        const int khn = tapn / 3, kwn = tapn - khn * 3;
#pragma unroll
        for (int p = 0; p < 2; ++p) {
          const size_t be = bbase[p] + (size_t)(khn * 34 + kwn) * 128 + icbn * 32;
          nbh[p] = *(const short8*)(xthi + be);
          nbl[p] = *(const short8*)(xtlo + be);
        }
      }
      const short8* __restrict__ a8h = (const short8*)ash[s & 1];
      const short8* __restrict__ a8l = (const short8*)asl[s & 1];
#pragma unroll
      for (int mt = 0; mt < 8; ++mt) {
        const short8 ah = a8h[mt * 64 + lane];
        const short8 al = a8l[mt * 64 + lane];
#pragma unroll
        for (int p = 0; p < 2; ++p) {
          acc[mt][p] = __builtin_amdgcn_mfma_f32_16x16x32_bf16(ah, bh[p], acc[mt][p], 0, 0, 0);
          acc[mt][p] = __builtin_amdgcn_mfma_f32_16x16x32_bf16(ah, bl[p], acc[mt][p], 0, 0, 0);
          acc[mt][p] = __builtin_amdgcn_mfma_f32_16x16x32_bf16(al, bh[p], acc[mt][p], 0, 0, 0);
        }
      }
      if (s < 35) {
        // rotate B regs; write next A slice; one barrier per tap
#pragma unroll
        for (int p = 0; p < 2; ++p) { bh[p] = nbh[p]; bl[p] = nbl[p]; }
        const int nbuf = (s + 1) & 1;
        *(short8*)(ash[nbuf] + tid * 8) = rah0;
        *(short8*)(ash[nbuf] + (tid + 256) * 8) = rah1;
        *(short8*)(asl[nbuf] + tid * 8) = ral0;
        *(short8*)(asl[nbuf] + (tid + 256) * 8) = ral1;
        __syncthreads();
      }
    }
  }
#pragma unroll
  for (int p = 0; p < 2; ++p) {
    const size_t obase = (size_t)n * 128 * 1024 + pl[p];
#pragma unroll
    for (int mt = 0; mt < 8; ++mt) {
#pragma unroll
      for (int q = 0; q < 4; ++q) {
        const int cout = mt * 16 + kq * 4 + q;
        const float rr = fmaxf(acc[mt][p][q] + bias[cout], 0.f);
        const unsigned short h = bf16rn(rr);
        const size_t oi = obase + (size_t)cout * 1024;
        ench[oi] = (short)h;
        encl[oi] = (short)bf16rn(rr - __uint_as_float((unsigned)h << 16));
      }
    }
  }
}

// ---- vq_mfma (R14): block = (n, one 64-px block, all 128 ch) -------------
__global__ __launch_bounds__(256) void vq_mfma(
    const short* __restrict__ fhi, const short* __restrict__ flo,
    const short* __restrict__ ebh, const short* __restrict__ ebl,
    const float* __restrict__ nrm, const float* __restrict__ emb,
    short* __restrict__ d1h) {
  __shared__ int sidx[128];
  const int lane = threadIdx.x & 63;
  const int wave = threadIdx.x >> 6;
  const int n  = blockIdx.x >> 4;
  const int pb = blockIdx.x & 15;

  short8 ah0[2], ah1[2], al0[2], al1[2];
#pragma unroll
  for (int g = 0; g < 2; ++g) {
    const int ch = wave * 32 + g * 16 + (lane & 15);
    const size_t abase = (((size_t)(n * 128 + ch)) * 16 + pb) * 64 + ((lane >> 4) << 3);
    ah0[g] = *(const short8*)(fhi + abase);
    ah1[g] = *(const short8*)(fhi + abase + 32);
    al0[g] = *(const short8*)(flo + abase);
    al1[g] = *(const short8*)(flo + abase + 32);
  }

  float bestv[2][4];
  int   besti[2][4];
#pragma unroll
  for (int g = 0; g < 2; ++g)
#pragma unroll
    for (int q = 0; q < 4; ++q) { bestv[g][q] = 3.4e38f; besti[g][q] = 0; }

  const short8* __restrict__ ebh8 = (const short8*)ebh;
  const short8* __restrict__ ebl8 = (const short8*)ebl;
  for (int ct = 0; ct < 32; ++ct) {
    const int f0 = (ct * 2) * 64 + lane;
    const short8 b0h = ebh8[f0];
    const short8 b1h = ebh8[f0 + 64];
    const short8 b0l = ebl8[f0];
    const short8 b1l = ebl8[f0 + 64];
    const int code = ct * 16 + (lane & 15);
    const float nn = nrm[code];
#pragma unroll
    for (int g = 0; g < 2; ++g) {
      floatx4 acc = {0.f, 0.f, 0.f, 0.f};
      acc = __builtin_amdgcn_mfma_f32_16x16x32_bf16(ah0[g], b0h, acc, 0, 0, 0);
      acc = __builtin_amdgcn_mfma_f32_16x16x32_bf16(ah1[g], b1h, acc, 0, 0, 0);
      acc = __builtin_amdgcn_mfma_f32_16x16x32_bf16(ah0[g], b0l, acc, 0, 0, 0);
      acc = __builtin_amdgcn_mfma_f32_16x16x32_bf16(ah1[g], b1l, acc, 0, 0, 0);
      acc = __builtin_amdgcn_mfma_f32_16x16x32_bf16(al0[g], b0h, acc, 0, 0, 0);
      acc = __builtin_amdgcn_mfma_f32_16x16x32_bf16(al1[g], b1h, acc, 0, 0, 0);
#pragma unroll
      for (int q = 0; q < 4; ++q) {
        const float sc = nn - 2.f * acc[q];
        if (sc < bestv[g][q]) { bestv[g][q] = sc; besti[g][q] = code; }
      }
    }
  }
#pragma unroll
  for (int off = 1; off < 16; off <<= 1) {
#pragma unroll
    for (int g = 0; g < 2; ++g)
#pragma unroll
      for (int q = 0; q < 4; ++q) {
        const float ov = __shfl_xor(bestv[g][q], off, 64);
        const int   oi = __shfl_xor(besti[g][q], off, 64);
        if (ov < bestv[g][q] || (ov == bestv[g][q] && oi < besti[g][q])) {
          bestv[g][q] = ov; besti[g][q] = oi;
        }
      }
  }
  if ((lane & 15) == 0) {
#pragma unroll
    for (int g = 0; g < 2; ++g)
#pragma unroll
      for (int q = 0; q < 4; ++q)
        sidx[wave * 32 + g * 16 + (lane >> 4) * 4 + q] = besti[g][q];
  }
  __syncthreads();
  const int chg = (threadIdx.x & 15) * 8;
  int gi8[8];
#pragma unroll
  for (int k = 0; k < 8; ++k) gi8[k] = sidx[chg + k];
#pragma unroll
  for (int pxg = 0; pxg < 4; ++pxg) {
    const int p = pxg * 16 + (threadIdx.x >> 4);   // 0..63
    const int pix = pb * 64 + p;
    const int r = pix >> 5, c = pix & 31;
    short8 v;
#pragma unroll
    for (int k = 0; k < 8; ++k)
      v[k] = (short)bf16rn(emb[(size_t)gi8[k] * 64 + p]);
    *(short8*)(d1h + (((size_t)n * 34 + r + 1) * 34 + (c + 1)) * 128 + chg) = v;
  }
}

// ---------------- dec3: fp32 direct from single-bf16 xt input -------------
__global__ __launch_bounds__(256) void dec3_xt(const short* __restrict__ xh,
                                               const float* __restrict__ w,
                                               const float* __restrict__ bias,
                                               float* __restrict__ out, int NH) {
  int t = blockIdx.x * 256 + threadIdx.x;
  if (t >= NH * 128 * 128) return;
  const int px = t & 16383;
  const int nl = t >> 14;
  const int i = px >> 7, j = px & 127;
  const float b0 = bias[0];
  float a00 = b0, a01 = b0, a10 = b0, a11 = b0;
  const size_t base00 = (((size_t)nl * 130 + i + 1) * 130 + (j + 1)) * 32;
#pragma unroll
  for (int icg = 0; icg < 4; ++icg) {
    const short8 h00 = *(const short8*)(xh + base00 + icg * 8);
    const short8 h01 = *(const short8*)(xh + base00 + 32 + icg * 8);
    const short8 h10 = *(const short8*)(xh + base00 + 130 * 32 + icg * 8);
    const short8 h11 = *(const short8*)(xh + base00 + 130 * 32 + 32 + icg * 8);
#pragma unroll
    for (int kk = 0; kk < 8; ++kk) {
      const int ic = icg * 8 + kk;
      const float x00 = bf2f1(h00[kk]);
      const float x01 = bf2f1(h01[kk]);
      const float x10 = bf2f1(h10[kk]);
      const float x11 = bf2f1(h11[kk]);
      const float* wp = w + ic * 9;
      a00 = fmaf(x00, wp[4], a00);
      a01 = fmaf(x00, wp[5], fmaf(x01, wp[3], a01));
      a10 = fmaf(x00, wp[7], fmaf(x10, wp[1], a10));
      a11 = fmaf(x00, wp[8], fmaf(x01, wp[6], fmaf(x10, wp[2], fmaf(x11, wp[0], a11))));
    }
  }
  float* op = out + ((size_t)nl * 256 + 2 * i) * 256 + 2 * j;
  op[0] = a00; op[1] = a01; op[256] = a10; op[257] = a11;
}

// ---------------------------------------------------------------------------
extern "C" void kernel_launch(void* const* d_in, const int* in_sizes, int n_in,
                              void* d_out, int out_size, void* d_ws, size_t ws_size,
                              hipStream_t stream) {
  const float* x   = (const float*)d_in[0];
  const float* w1  = (const float*)d_in[1];
  const float* b1  = (const float*)d_in[2];
  const float* w2  = (const float*)d_in[3];
  const float* b2  = (const float*)d_in[4];
  const float* w3  = (const float*)d_in[5];
  const float* b3  = (const float*)d_in[6];
  const float* w4  = (const float*)d_in[7];
  const float* b4  = (const float*)d_in[8];
  const float* emb = (const float*)d_in[9];
  const float* dw1 = (const float*)d_in[10];
  const float* db1 = (const float*)d_in[11];
  const float* dw2 = (const float*)d_in[12];
  const float* db2 = (const float*)d_in[13];
  const float* dw3 = (const float*)d_in[14];
  const float* db3 = (const float*)d_in[15];
  float* outp = (float*)d_out;

  const int N = in_sizes[0] / (2 * 256 * 256);  // 64
  if (N & 1) return;
  const int NH = N / 2;

  // ---- arena (units: floats; 1 float = 2 shorts); R7-proven footprint ----
  const size_t sx3 = (size_t)N * 66 * 66 * 64;
  const size_t sx2 = (size_t)NH * 130 * 130 * 32;
  const size_t sx4 = (size_t)N * 34 * 34 * 128;
  const size_t se  = (size_t)N * 128 * 1024;
  const size_t sd1 = sx4;
  const size_t smalls = 512 + 18432 + 73728 + 147456 + 73728 + 18432 + 32768;
  const size_t need = (sx3 + sx4 + se + sd1 + smalls) * sizeof(float);
  if (ws_size < need) return;

  float* ws = (float*)d_ws;
  short* x3h = (short*)ws;                 short* x3l = x3h + sx3;   // enc split
  short* x2h = (short*)(ws + sx3);         short* x2l = x2h + sx2;
  short* x4h = (short*)(ws + sx3);         short* x4l = x4h + sx4;
  short* ech = (short*)(ws + sx3 + sx4);   short* ecl = ech + se;
  short* d1h = (short*)(ws + sx3 + sx4 + se);   // bf16-only decoder bufs
  short* d2h = (short*)ws;
  short* d3h = (short*)(ws + sx3);
  float* sm  = ws + sx3 + sx4 + se + sd1;
  float* nrm = sm;
  short* a2h = (short*)(sm + 512);                         short* a2l = a2h + 18432;
  short* a3h = (short*)(sm + 512 + 18432);                 short* a3l = a3h + 73728;
  short* a4h = (short*)(sm + 512 + 18432 + 73728);         short* a4l = a4h + 147456;
  short* ad1h = (short*)(sm + 512 + 18432 + 73728 + 147456);           // hi only
  short* ad2h = (short*)(sm + 512 + 18432 + 73728 + 147456 + 73728);   // hi only
  short* ebh = (short*)(sm + 512 + 18432 + 73728 + 147456 + 73728 + 18432); short* ebl = ebh + 32768;

  // ---- fused weight preps + VQ tables (R15) ----
  prep_all<<<1426, 256, 0, stream>>>(w2, w3, w4, dw1, dw2, emb,
                                     a2h, a2l, a3h, a3l, a4h, a4l,
                                     ad1h, ad2h, nrm, ebh, ebl);

  // ---- encoder (split-bf16, NP=2; A-LDS staged) ----
  ring_zero<<<(int)((NH * 516 * 32 + 255) / 256), 256, 0, stream>>>(x2h, x2l, NH, 130, 130, 32);
  ring_zero<<<(int)(((size_t)N * 260 * 64 + 255) / 256), 256, 0, stream>>>(x3h, x3l, N, 66, 66, 64);
  for (int half = 0; half < 2; ++half) {
    const int n0 = half * NH;
    conv1_xt<<<NH * 16384 / 256, 256, 0, stream>>>(
        x + (size_t)n0 * 2 * 65536, w1, b1, x2h, x2l, NH);
    conv_mfma_xt<32, 64, 64, 64, 2, 130, 130, 66, 66, 2>
        <<<NH * 32, 256, 0, stream>>>(x2h, x2l, a2h, a2l, b2,
                                      x3h + (size_t)n0 * 66 * 66 * 64,
                                      x3l + (size_t)n0 * 66 * 66 * 64);
  }
  ring_zero<<<(int)(((size_t)N * 132 * 128 + 255) / 256), 256, 0, stream>>>(x4h, x4l, N, 34, 34, 128);
  conv_mfma_xt<64, 128, 32, 32, 2, 66, 66, 34, 34, 2>
      <<<N * 8, 256, 0, stream>>>(x3h, x3l, a3h, a3l, b3, x4h, x4l);
  conv4_mfma<<<N * 8, 256, 0, stream>>>(x4h, x4l, a4h, a4l, b4, ech, ecl);

  // ---- VQ (split scoring, bf16 gather; R14 coalesced) ----
  ring_zero1<<<(int)(((size_t)N * 132 * 128 + 255) / 256), 256, 0, stream>>>(d1h, N, 34, 34, 128);
  vq_mfma<<<N * 16, 256, 0, stream>>>(ech, ecl, ebh, ebl, nrm, emb, d1h);

  // ---- decoder (plain bf16, NP=2; deconv1 A-LDS staged) ----
  ring_zero1<<<(int)(((size_t)N * 260 * 64 + 255) / 256), 256, 0, stream>>>(d2h, N, 66, 66, 64);
  deconv_bf16_xt<128, 64, 32, 32, 34, 34, 66, 66, 2, 1>
      <<<N * 8, 256, 0, stream>>>(d1h, ad1h, db1, d2h);
  ring_zero1<<<(int)((NH * 516 * 32 + 255) / 256), 256, 0, stream>>>(d3h, NH, 130, 130, 32);
  for (int half = 0; half < 2; ++half) {
    const int n0 = half * NH;
    deconv_bf16_xt<64, 32, 64, 64, 66, 66, 130, 130, 2, 0>
        <<<NH * 32, 256, 0, stream>>>(d2h + (size_t)n0 * 66 * 66 * 64,
                                      ad2h, db2, d3h);
    dec3_xt<<<NH * 16384 / 256, 256, 0, stream>>>(
        d3h, dw3, db3, outp + (size_t)n0 * 65536, NH);
  }
}

// Round 11
// 542.064 us; speedup vs baseline: 1.1540x; 1.1540x over previous
//
#include <hip/hip_runtime.h>

// ---------------------------------------------------------------------------
// VQ-VAE forward (NCHW). Round 20: conv4 = R17 + 2-tap A staging (18 barriers).
//  R19 post-mortem: B reg-prefetch regressed (76.7->85.5us) -- compiler
//  drains vmcnt(0) at every __syncthreads anyway, so prefetched loads still
//  gated each barrier; only overhead was added. Reverted B to just-in-time.
//  Conv4 ledger: R17 (76.7us) best; failed levers: fewer waves (R16), more
//  waves (R18), B-prefetch (R19), B-LDS (R11), cross-block splits (R10).
//  Remaining lever: barrier count. Per-tap budget ~2100cy throughput vs
//  ~5100cy measured -> ~3000cy drain/latency per tap across 36 barriers.
//  Change: A staged 2 tap-slices per LDS buffer (2x16KB buffers, 64KB
//  total, still 2 blocks/CU), prefetch next PAIR once per super-tap,
//  one barrier per 2 taps (18 total), 96 MFMAs between barriers.
//  A bytes, B addressing, per-acc MFMA order unchanged -> absmax 2.441e-4.
//  All other kernels identical to R17 (548us best-total config).
// ---------------------------------------------------------------------------

using short8  = __attribute__((ext_vector_type(8))) short;
using short4v = __attribute__((ext_vector_type(4))) short;
using floatx4 = __attribute__((ext_vector_type(4))) float;

__device__ inline unsigned short bf16rn(float f) {
  unsigned u = __float_as_uint(f);
  unsigned r = (u + 0x7fffu + ((u >> 16) & 1u)) >> 16;
  return (unsigned short)r;
}
__device__ inline float bf2f1(short h) {
  return __uint_as_float(((unsigned)(unsigned short)h) << 16);
}

// ---- deconv tap tables: entry e -> (ky,kx) weight tap
__device__ const int DKY[9]  = {1, 1, 1, 2, 0, 2, 2, 0, 0};
__device__ const int DKX[9]  = {1, 2, 0, 1, 1, 2, 0, 2, 0};

// ---------------- ring zero (split pair) ----------------------------------
__global__ __launch_bounds__(256) void ring_zero(short* __restrict__ h,
                                                 short* __restrict__ l,
                                                 int nimg, int PH, int PW, int C) {
  const int RC = (2 * PW + 2 * (PH - 2)) * C;
  int t = blockIdx.x * 256 + threadIdx.x;
  if (t >= nimg * RC) return;
  const int nl = t / RC;
  int rem = t - nl * RC;
  const int p = rem / C;
  const int ch = rem - p * C;
  int r, c;
  if (p < 2 * PW) {
    r = (p < PW) ? 0 : PH - 1;
    c = (p < PW) ? p : p - PW;
  } else {
    int q = p - 2 * PW;
    if (q < PH - 2) { r = 1 + q; c = 0; }
    else { r = 1 + q - (PH - 2); c = PW - 1; }
  }
  const size_t a = (((size_t)nl * PH + r) * PW + c) * C + ch;
  h[a] = 0; l[a] = 0;
}

// ---------------- ring zero (single buffer) -------------------------------
__global__ __launch_bounds__(256) void ring_zero1(short* __restrict__ h,
                                                  int nimg, int PH, int PW, int C) {
  const int RC = (2 * PW + 2 * (PH - 2)) * C;
  int t = blockIdx.x * 256 + threadIdx.x;
  if (t >= nimg * RC) return;
  const int nl = t / RC;
  int rem = t - nl * RC;
  const int p = rem / C;
  const int ch = rem - p * C;
  int r, c;
  if (p < 2 * PW) {
    r = (p < PW) ? 0 : PH - 1;
    c = (p < PW) ? p : p - PW;
  } else {
    int q = p - 2 * PW;
    if (q < PH - 2) { r = 1 + q; c = 0; }
    else { r = 1 + q - (PH - 2); c = PW - 1; }
  }
  h[(((size_t)nl * PH + r) * PW + c) * C + ch] = 0;
}

// ---------------- conv1: fp32 direct, writes xt [nh][130][130][32] --------
__global__ __launch_bounds__(256) void conv1_xt(const float* __restrict__ x,
                                                const float* __restrict__ w,
                                                const float* __restrict__ bias,
                                                short* __restrict__ oh,
                                                short* __restrict__ ol, int NH) {
  int t = blockIdx.x * 256 + threadIdx.x;
  if (t >= NH * 128 * 128) return;
  const int px = t & 16383;
  const int n  = t >> 14;
  const int r = px >> 7, c = px & 127;
  const int ih0 = 2 * r - 1, iw0 = 2 * c - 1;
  float acc[32];
#pragma unroll
  for (int o = 0; o < 32; ++o) acc[o] = bias[o];
  const float* ip = x + (size_t)n * 2 * 65536;
#pragma unroll
  for (int ic = 0; ic < 2; ++ic, ip += 65536) {
    float v[9];
#pragma unroll
    for (int kh = 0; kh < 3; ++kh) {
      const int ih = ih0 + kh;
#pragma unroll
      for (int kw = 0; kw < 3; ++kw) {
        const int iw = iw0 + kw;
        const bool ok = (ih >= 0) && (ih < 256) && (iw < 256) && (iw >= 0);
        v[kh * 3 + kw] = ok ? ip[ih * 256 + iw] : 0.f;
      }
    }
#pragma unroll
    for (int o = 0; o < 32; ++o) {
      float s = acc[o];
#pragma unroll
      for (int k = 0; k < 9; ++k) s = fmaf(v[k], w[(o * 2 + ic) * 9 + k], s);
      acc[o] = s;
    }
  }
  const size_t base = (((size_t)n * 130 + r + 1) * 130 + (c + 1)) * 32;
  short8 vh[4], vl[4];
#pragma unroll
  for (int g = 0; g < 4; ++g) {
#pragma unroll
    for (int kk = 0; kk < 8; ++kk) {
      const float rv = fmaxf(acc[g * 8 + kk], 0.f);
      const unsigned short hh = bf16rn(rv);
      vh[g][kk] = (short)hh;
      vl[g][kk] = (short)bf16rn(rv - __uint_as_float((unsigned)hh << 16));
    }
    *(short8*)(oh + base + g * 8) = vh[g];
    *(short8*)(ol + base + g * 8) = vl[g];
  }
}

// ---------------- fused weight/table prep (R15) ---------------------------
template<int CIN, int COUT>
__device__ inline void wprep_conv_body(int t, const float* __restrict__ w,
                                       short* __restrict__ hi,
                                       short* __restrict__ lo) {
  constexpr int MT = COUT / 16;
  const int j = t & 7;
  const int lane = (t >> 3) & 63;
  const int g = t >> 9;
  const int mt = g % MT;
  const int s = g / MT;
  const int icb = s / 9, tap = s - icb * 9;
  const int kh = tap / 3, kw = tap - kh * 3;
  const int m = mt * 16 + (lane & 15);
  const int ic = icb * 32 + ((lane >> 4) << 3) + j;
  const float v = w[((m * CIN + ic) * 3 + kh) * 3 + kw];
  const unsigned short h = bf16rn(v);
  hi[t] = (short)h;
  lo[t] = (short)bf16rn(v - __uint_as_float((unsigned)h << 16));
}

template<int CIN, int COUT>
__device__ inline void wprep_dec_body(int t, const float* __restrict__ w,
                                      short* __restrict__ hi) {
  constexpr int MT = COUT / 16, ICB = CIN / 32;
  const int j = t & 7;
  const int lane = (t >> 3) & 63;
  const int g = t >> 9;
  const int mt = g % MT;
  const int u = g / MT;
  const int icb = u % ICB;
  const int e = u / ICB;
  const int ky = DKY[e], kx = DKX[e];
  const int m = mt * 16 + (lane & 15);
  const int ic = icb * 32 + ((lane >> 4) << 3) + j;
  hi[t] = (short)bf16rn(w[((ic * COUT + m) * 3 + ky) * 3 + kx]);
}

__global__ __launch_bounds__(256) void prep_all(
    const float* __restrict__ w2, const float* __restrict__ w3,
    const float* __restrict__ w4, const float* __restrict__ dw1,
    const float* __restrict__ dw2, const float* __restrict__ emb,
    short* __restrict__ a2h, short* __restrict__ a2l,
    short* __restrict__ a3h, short* __restrict__ a3l,
    short* __restrict__ a4h, short* __restrict__ a4l,
    short* __restrict__ ad1h, short* __restrict__ ad2h,
    float* __restrict__ nrm, short* __restrict__ ebh,
    short* __restrict__ ebl) {
  const int bb = blockIdx.x;
  const int tid = threadIdx.x;
  if (bb < 72) {
    wprep_conv_body<32, 64>(bb * 256 + tid, w2, a2h, a2l);
  } else if (bb < 360) {
    wprep_conv_body<64, 128>((bb - 72) * 256 + tid, w3, a3h, a3l);
  } else if (bb < 936) {
    wprep_conv_body<128, 128>((bb - 360) * 256 + tid, w4, a4h, a4l);
  } else if (bb < 1224) {
    wprep_dec_body<128, 64>((bb - 936) * 256 + tid, dw1, ad1h);
  } else if (bb < 1296) {
    wprep_dec_body<64, 32>((bb - 1224) * 256 + tid, dw2, ad2h);
  } else if (bb < 1424) {
    const int t = (bb - 1296) * 256 + tid;   // < 32768
    const int j  = t & 7;
    const int l  = (t >> 3) & 63;
    const int kk = (t >> 9) & 1;
    const int ct = t >> 10;
    const int code = ct * 16 + (l & 15);
    const int k = kk * 32 + ((l >> 4) << 3) + j;
    const float v = emb[code * 64 + k];
    const unsigned short h = bf16rn(v);
    ebh[t] = (short)h;
    ebl[t] = (short)bf16rn(v - __uint_as_float((unsigned)h << 16));
  } else {
    const int jj = (bb - 1424) * 256 + tid;
    if (jj < 512) {
      float s = 0.f;
      const float* e = emb + jj * 64;
#pragma unroll
      for (int k = 0; k < 64; ++k) s = fmaf(e[k], e[k], s);
      nrm[jj] = s;
    }
  }
}

// ------- generic strided conv MFMA (split xt -> split xt), NP tiles -------
// R15: per-tap A-slice LDS staging, double-buffered.
template<int CIN, int COUT, int OH, int OW, int S, int PHI, int PWI, int PHO, int PWO, int NP>
__global__ __launch_bounds__(256) void conv_mfma_xt(
    const short* __restrict__ xih, const short* __restrict__ xil,
    const short* __restrict__ ah,  const short* __restrict__ al,
    const float* __restrict__ bias,
    short* __restrict__ xoh, short* __restrict__ xol) {
  constexpr int MT = COUT / 16, ICB = CIN / 32;
  constexpr int PXB = 64 * NP, TPB = OH * OW / PXB;
  constexpr int NSL = ICB * 9;            // total A slices
  constexpr int CH  = MT * 64;            // short8 chunks per slice (hi or lo)
  constexpr int CPT = (CH + 255) / 256;   // chunks per thread
  __shared__ short ash[2][CH * 8];
  __shared__ short asl2[2][CH * 8];
  const int b = blockIdx.x;
  const int n = b / TPB, pt = b % TPB;
  const int tid = threadIdx.x;
  const int lane = tid & 63, wave = tid >> 6;
  const int quad = lane >> 4;
  int rr[NP], cc[NP];
  size_t bbase[NP];
#pragma unroll
  for (int p = 0; p < NP; ++p) {
    const int pl = pt * PXB + wave * (16 * NP) + p * 16 + (lane & 15);
    rr[p] = pl / OW; cc[p] = pl % OW;
    bbase[p] = (((size_t)n * PHI + S * rr[p]) * PWI + S * cc[p]) * CIN + quad * 8;
  }

  floatx4 acc[MT][NP];
#pragma unroll
  for (int mt = 0; mt < MT; ++mt)
#pragma unroll
    for (int p = 0; p < NP; ++p) acc[mt][p] = (floatx4){0.f, 0.f, 0.f, 0.f};

  const short8* __restrict__ ah8 = (const short8*)ah;
  const short8* __restrict__ al8 = (const short8*)al;

  // prologue: stage A slice 0 into buffer 0
  short8 ra[CPT], rl[CPT];
#pragma unroll
  for (int c = 0; c < CPT; ++c) {
    const int idx = tid + c * 256;
    if (idx < CH) { ra[c] = ah8[idx]; rl[c] = al8[idx]; }
  }
#pragma unroll
  for (int c = 0; c < CPT; ++c) {
    const int idx = tid + c * 256;
    if (idx < CH) {
      *(short8*)(ash[0] + idx * 8) = ra[c];
      *(short8*)(asl2[0] + idx * 8) = rl[c];
    }
  }
  __syncthreads();

  int s = 0;
  for (int icb = 0; icb < ICB; ++icb) {
#pragma unroll
    for (int tap = 0; tap < 9; ++tap, ++s) {
      // prefetch next A slice into regs (hides under MFMAs)
      if (s + 1 < NSL) {
        const int base = (s + 1) * CH;
#pragma unroll
        for (int c = 0; c < CPT; ++c) {
          const int idx = tid + c * 256;
          if (idx < CH) { ra[c] = ah8[base + idx]; rl[c] = al8[base + idx]; }
        }
      }
      const int kh = tap / 3, kw = tap - kh * 3;
      short8 bh[NP], bl[NP];
#pragma unroll
      for (int p = 0; p < NP; ++p) {
        const size_t be = bbase[p] + (size_t)(kh * PWI + kw) * CIN + icb * 32;
        bh[p] = *(const short8*)(xih + be);
        bl[p] = *(const short8*)(xil + be);
      }
      const short8* __restrict__ a8h = (const short8*)ash[s & 1];
      const short8* __restrict__ a8l = (const short8*)asl2[s & 1];
#pragma unroll
      for (int mt = 0; mt < MT; ++mt) {
        const short8 wh = a8h[mt * 64 + lane];
        const short8 wl = a8l[mt * 64 + lane];
#pragma unroll
        for (int p = 0; p < NP; ++p) {
          acc[mt][p] = __builtin_amdgcn_mfma_f32_16x16x32_bf16(wh, bh[p], acc[mt][p], 0, 0, 0);
          acc[mt][p] = __builtin_amdgcn_mfma_f32_16x16x32_bf16(wh, bl[p], acc[mt][p], 0, 0, 0);
          acc[mt][p] = __builtin_amdgcn_mfma_f32_16x16x32_bf16(wl, bh[p], acc[mt][p], 0, 0, 0);
        }
      }
      if (s + 1 < NSL) {
        const int nb = (s + 1) & 1;
#pragma unroll
        for (int c = 0; c < CPT; ++c) {
          const int idx = tid + c * 256;
          if (idx < CH) {
            *(short8*)(ash[nb] + idx * 8) = ra[c];
            *(short8*)(asl2[nb] + idx * 8) = rl[c];
          }
        }
        __syncthreads();
      }
    }
  }
#pragma unroll
  for (int p = 0; p < NP; ++p) {
    const size_t ob = (((size_t)n * PHO + rr[p] + 1) * PWO + (cc[p] + 1)) * COUT + quad * 4;
#pragma unroll
    for (int mt = 0; mt < MT; ++mt) {
      short4v sh, sl;
#pragma unroll
      for (int q = 0; q < 4; ++q) {
        const float v = fmaxf(acc[mt][p][q] + bias[mt * 16 + quad * 4 + q], 0.f);
        const unsigned short hh = bf16rn(v);
        sh[q] = (short)hh;
        sl[q] = (short)bf16rn(v - __uint_as_float((unsigned)hh << 16));
      }
      *(short4v*)(xoh + ob + mt * 16) = sh;
      *(short4v*)(xol + ob + mt * 16) = sl;
    }
  }
}

// ---- fused transposed conv, plain bf16, NP pixel-tiles per wave ----------
// R15: ASTG=1 stages the per-icb A group (9 e-slices) in LDS, double-buffered.
template<int CIN, int COUT, int IH, int IW, int PHI, int PWI, int PHO, int PWO, int NP, int ASTG>
__global__ __launch_bounds__(256) void deconv_bf16_xt(
    const short* __restrict__ xih, const short* __restrict__ ah,
    const float* __restrict__ bias, short* __restrict__ xoh) {
  constexpr int MT = COUT / 16, ICB = CIN / 32;
  constexpr int PXB = 64 * NP, TPB = IH * IW / PXB;
  constexpr int CHI = 9 * MT * 64;               // chunks per icb A-group
  constexpr int CPT = (CHI + 255) / 256;
  constexpr int PHE[9] = {0, 1, 1, 2, 2, 3, 3, 3, 3};
  constexpr int DE[9]  = {0, 0, 1, 0, 2, 0, 1, 2, 3};
  __shared__ short ash[ASTG ? 2 * CHI * 8 : 1];
  const int b = blockIdx.x;
  const int n = b / TPB, pt = b % TPB;
  const int tid = threadIdx.x;
  const int lane = tid & 63, wave = tid >> 6;
  const int quad = lane >> 4;
  int ii[NP], jj[NP];
  size_t p00[NP];
#pragma unroll
  for (int p = 0; p < NP; ++p) {
    const int pl = pt * PXB + wave * (16 * NP) + p * 16 + (lane & 15);
    ii[p] = pl / IW; jj[p] = pl % IW;
    p00[p] = (((size_t)n * PHI + (ii[p] + 1)) * PWI + (jj[p] + 1)) * CIN + quad * 8;
  }

  floatx4 acc[4][MT][NP];
#pragma unroll
  for (int ph = 0; ph < 4; ++ph)
#pragma unroll
    for (int mt = 0; mt < MT; ++mt)
#pragma unroll
      for (int p = 0; p < NP; ++p) acc[ph][mt][p] = (floatx4){0.f, 0.f, 0.f, 0.f};

  const short8* __restrict__ ah8 = (const short8*)ah;

  short8 ra[ASTG ? CPT : 1];
  if constexpr (ASTG) {
    // prologue: stage icb0's 9 e-slices into buffer 0
#pragma unroll
    for (int c = 0; c < CPT; ++c) {
      const int idx = tid + c * 256;
      if (idx < CHI) {
        const int e = idx / (MT * 64);
        const int rem = idx - e * (MT * 64);
        ra[c] = ah8[(e * ICB + 0) * (MT * 64) + rem];
      }
    }
#pragma unroll
    for (int c = 0; c < CPT; ++c) {
      const int idx = tid + c * 256;
      if (idx < CHI) *(short8*)(ash + idx * 8) = ra[c];
    }
    __syncthreads();
  }

  for (int icb = 0; icb < ICB; ++icb) {
    short8 bh[NP][4];
#pragma unroll
    for (int p = 0; p < NP; ++p)
#pragma unroll
      for (int d = 0; d < 4; ++d)
        bh[p][d] = *(const short8*)(xih + p00[p] +
                                    (size_t)((d >> 1) * PWI + (d & 1)) * CIN + icb * 32);
    if constexpr (ASTG) {
      if (icb + 1 < ICB) {
#pragma unroll
        for (int c = 0; c < CPT; ++c) {
          const int idx = tid + c * 256;
          if (idx < CHI) {
            const int e = idx / (MT * 64);
            const int rem = idx - e * (MT * 64);
            ra[c] = ah8[(e * ICB + icb + 1) * (MT * 64) + rem];
          }
        }
      }
    }
#pragma unroll
    for (int e = 0; e < 9; ++e) {
      const int ph = PHE[e], d = DE[e];
#pragma unroll
      for (int mt = 0; mt < MT; ++mt) {
        short8 wh;
        if constexpr (ASTG)
          wh = ((const short8*)(ash + (size_t)(icb & 1) * CHI * 8))[(e * MT + mt) * 64 + lane];
        else
          wh = ah8[((e * ICB + icb) * MT + mt) * 64 + lane];
#pragma unroll
        for (int p = 0; p < NP; ++p)
          acc[ph][mt][p] = __builtin_amdgcn_mfma_f32_16x16x32_bf16(
              wh, bh[p][d], acc[ph][mt][p], 0, 0, 0);
      }
    }
    if constexpr (ASTG) {
      if (icb + 1 < ICB) {
        const size_t nb = (size_t)((icb + 1) & 1) * CHI * 8;
#pragma unroll
        for (int c = 0; c < CPT; ++c) {
          const int idx = tid + c * 256;
          if (idx < CHI) *(short8*)(ash + nb + idx * 8) = ra[c];
        }
        __syncthreads();
      }
    }
  }
#pragma unroll
  for (int p = 0; p < NP; ++p)
#pragma unroll
    for (int ph = 0; ph < 4; ++ph) {
      const int oy = 2 * ii[p] + (ph >> 1), ox = 2 * jj[p] + (ph & 1);
      const size_t ob = (((size_t)n * PHO + oy + 1) * PWO + (ox + 1)) * COUT + quad * 4;
#pragma unroll
      for (int mt = 0; mt < MT; ++mt) {
        short4v sh;
#pragma unroll
        for (int q = 0; q < 4; ++q)
          sh[q] = (short)bf16rn(fmaxf(acc[ph][mt][p][q] + bias[mt * 16 + quad * 4 + q], 0.f));
        *(short4v*)(xoh + ob + mt * 16) = sh;
      }
    }
}

// ---------------- conv4 MFMA (R20): A staged 2 taps/buffer, 18 barriers ---
// 256 thr, 4 waves, grid N*8, NP=2; B just-in-time from global (R17);
// A: 2 buffers x 2 tap-slices (64KB LDS), prefetch next pair per super-tap.
__global__ __launch_bounds__(256) void conv4_mfma(
    const short* __restrict__ xthi, const short* __restrict__ xtlo,
    const short* __restrict__ ahi,  const short* __restrict__ alo,
    const float* __restrict__ bias,
    short* __restrict__ ench, short* __restrict__ encl) {
  __shared__ short ash[2][8192];        // 2 x 16384 B (A hi, two tap slices)
  __shared__ short asl[2][8192];        // 2 x 16384 B (A lo)
  const int b    = blockIdx.x;          // N*8 blocks, 128 pixels each
  const int n    = b >> 3;
  const int pt   = b & 7;
  const int tid  = threadIdx.x;
  const int lane = tid & 63;
  const int wave = tid >> 6;
  const int kq   = lane >> 4;
  int pl[2];
  size_t bbase[2];
#pragma unroll
  for (int p = 0; p < 2; ++p) {
    pl[p] = pt * 128 + wave * 32 + p * 16 + (lane & 15);
    const int r = pl[p] >> 5, c = pl[p] & 31;
    bbase[p] = (((size_t)n * 34 + r) * 34 + c) * 128 + kq * 8;
  }

  floatx4 acc[8][2];
#pragma unroll
  for (int mt = 0; mt < 8; ++mt)
#pragma unroll
    for (int p = 0; p < 2; ++p) acc[mt][p] = (floatx4){0.f, 0.f, 0.f, 0.f};

  const short8* __restrict__ ah8 = (const short8*)ahi;
  const short8* __restrict__ al8 = (const short8*)alo;

  // A prologue: stage tap-slices 0,1 (1024 chunks each of hi/lo) into buf 0
  short8 rah[4], ral[4];
#pragma unroll
  for (int c = 0; c < 4; ++c) {
    rah[c] = ah8[tid + c * 256];
    ral[c] = al8[tid + c * 256];
  }
#pragma unroll
  for (int c = 0; c < 4; ++c) {
    *(short8*)(ash[0] + (tid + c * 256) * 8) = rah[c];
    *(short8*)(asl[0] + (tid + c * 256) * 8) = ral[c];
  }
  __syncthreads();

  for (int st = 0; st < 18; ++st) {
    // prefetch next super-tap's 2 A slices into regs
    if (st < 17) {
      const int nb = (st + 1) * 1024;
#pragma unroll
      for (int c = 0; c < 4; ++c) {
        rah[c] = ah8[nb + tid + c * 256];
        ral[c] = al8[nb + tid + c * 256];
      }
    }
#pragma unroll
    for (int t2 = 0; t2 < 2; ++t2) {
      const int s = st * 2 + t2;
      const int icb = s / 9, tap = s - icb * 9;
      const int kh = tap / 3, kw = tap - kh * 3;
      const short8* __restrict__ a8h = (const short8*)ash[st & 1] + t2 * 512;
      const short8* __restrict__ a8l = (const short8*)asl[st & 1] + t2 * 512;
      short8 bh[2], bl[2];
#pragma unroll
      for (int p = 0; p < 2; ++p) {
        const size_t be = bbase[p] + (size_t)(kh * 34 + kw) * 128 + icb * 32;
        bh[p] = *(const short8*)(xthi + be);
        bl[p] = *(const short8*)(xtlo + be);
      }
#pragma unroll
      for (int mt = 0; mt < 8; ++mt) {
        const short8 ah = a8h[mt * 64 + lane];
        const short8 al = a8l[mt * 64 + lane];
#pragma unroll
        for (int p = 0; p < 2; ++p) {
          acc[mt][p] = __builtin_amdgcn_mfma_f32_16x16x32_bf16(ah, bh[p], acc[mt][p], 0, 0, 0);
          acc[mt][p] = __builtin_amdgcn_mfma_f32_16x16x32_bf16(ah, bl[p], acc[mt][p], 0, 0, 0);
          acc[mt][p] = __builtin_amdgcn_mfma_f32_16x16x32_bf16(al, bh[p], acc[mt][p], 0, 0, 0);
        }
      }
    }
    if (st < 17) {
      const int nbuf = (st + 1) & 1;
#pragma unroll
      for (int c = 0; c < 4; ++c) {
        *(short8*)(ash[nbuf] + (tid + c * 256) * 8) = rah[c];
        *(short8*)(asl[nbuf] + (tid + c * 256) * 8) = ral[c];
      }
      __syncthreads();
    }
  }
#pragma unroll
  for (int p = 0; p < 2; ++p) {
    const size_t obase = (size_t)n * 128 * 1024 + pl[p];
#pragma unroll
    for (int mt = 0; mt < 8; ++mt) {
#pragma unroll
      for (int q = 0; q < 4; ++q) {
        const int cout = mt * 16 + kq * 4 + q;
        const float rr = fmaxf(acc[mt][p][q] + bias[cout], 0.f);
        const unsigned short h = bf16rn(rr);
        const size_t oi = obase + (size_t)cout * 1024;
        ench[oi] = (short)h;
        encl[oi] = (short)bf16rn(rr - __uint_as_float((unsigned)h << 16));
      }
    }
  }
}

// ---- vq_mfma (R14): block = (n, one 64-px block, all 128 ch) -------------
__global__ __launch_bounds__(256) void vq_mfma(
    const short* __restrict__ fhi, const short* __restrict__ flo,
    const short* __restrict__ ebh, const short* __restrict__ ebl,
    const float* __restrict__ nrm, const float* __restrict__ emb,
    short* __restrict__ d1h) {
  __shared__ int sidx[128];
  const int lane = threadIdx.x & 63;
  const int wave = threadIdx.x >> 6;
  const int n  = blockIdx.x >> 4;
  const int pb = blockIdx.x & 15;

  short8 ah0[2], ah1[2], al0[2], al1[2];
#pragma unroll
  for (int g = 0; g < 2; ++g) {
    const int ch = wave * 32 + g * 16 + (lane & 15);
    const size_t abase = (((size_t)(n * 128 + ch)) * 16 + pb) * 64 + ((lane >> 4) << 3);
    ah0[g] = *(const short8*)(fhi + abase);
    ah1[g] = *(const short8*)(fhi + abase + 32);
    al0[g] = *(const short8*)(flo + abase);
    al1[g] = *(const short8*)(flo + abase + 32);
  }

  float bestv[2][4];
  int   besti[2][4];
#pragma unroll
  for (int g = 0; g < 2; ++g)
#pragma unroll
    for (int q = 0; q < 4; ++q) { bestv[g][q] = 3.4e38f; besti[g][q] = 0; }

  const short8* __restrict__ ebh8 = (const short8*)ebh;
  const short8* __restrict__ ebl8 = (const short8*)ebl;
  for (int ct = 0; ct < 32; ++ct) {
    const int f0 = (ct * 2) * 64 + lane;
    const short8 b0h = ebh8[f0];
    const short8 b1h = ebh8[f0 + 64];
    const short8 b0l = ebl8[f0];
    const short8 b1l = ebl8[f0 + 64];
    const int code = ct * 16 + (lane & 15);
    const float nn = nrm[code];
#pragma unroll
    for (int g = 0; g < 2; ++g) {
      floatx4 acc = {0.f, 0.f, 0.f, 0.f};
      acc = __builtin_amdgcn_mfma_f32_16x16x32_bf16(ah0[g], b0h, acc, 0, 0, 0);
      acc = __builtin_amdgcn_mfma_f32_16x16x32_bf16(ah1[g], b1h, acc, 0, 0, 0);
      acc = __builtin_amdgcn_mfma_f32_16x16x32_bf16(ah0[g], b0l, acc, 0, 0, 0);
      acc = __builtin_amdgcn_mfma_f32_16x16x32_bf16(ah1[g], b1l, acc, 0, 0, 0);
      acc = __builtin_amdgcn_mfma_f32_16x16x32_bf16(al0[g], b0h, acc, 0, 0, 0);
      acc = __builtin_amdgcn_mfma_f32_16x16x32_bf16(al1[g], b1h, acc, 0, 0, 0);
#pragma unroll
      for (int q = 0; q < 4; ++q) {
        const float sc = nn - 2.f * acc[q];
        if (sc < bestv[g][q]) { bestv[g][q] = sc; besti[g][q] = code; }
      }
    }
  }
#pragma unroll
  for (int off = 1; off < 16; off <<= 1) {
#pragma unroll
    for (int g = 0; g < 2; ++g)
#pragma unroll
      for (int q = 0; q < 4; ++q) {
        const float ov = __shfl_xor(bestv[g][q], off, 64);
        const int   oi = __shfl_xor(besti[g][q], off, 64);
        if (ov < bestv[g][q] || (ov == bestv[g][q] && oi < besti[g][q])) {
          bestv[g][q] = ov; besti[g][q] = oi;
        }
      }
  }
  if ((lane & 15) == 0) {
#pragma unroll
    for (int g = 0; g < 2; ++g)
#pragma unroll
      for (int q = 0; q < 4; ++q)
        sidx[wave * 32 + g * 16 + (lane >> 4) * 4 + q] = besti[g][q];
  }
  __syncthreads();
  const int chg = (threadIdx.x & 15) * 8;
  int gi8[8];
#pragma unroll
  for (int k = 0; k < 8; ++k) gi8[k] = sidx[chg + k];
#pragma unroll
  for (int pxg = 0; pxg < 4; ++pxg) {
    const int p = pxg * 16 + (threadIdx.x >> 4);   // 0..63
    const int pix = pb * 64 + p;
    const int r = pix >> 5, c = pix & 31;
    short8 v;
#pragma unroll
    for (int k = 0; k < 8; ++k)
      v[k] = (short)bf16rn(emb[(size_t)gi8[k] * 64 + p]);
    *(short8*)(d1h + (((size_t)n * 34 + r + 1) * 34 + (c + 1)) * 128 + chg) = v;
  }
}

// ---------------- dec3: fp32 direct from single-bf16 xt input -------------
__global__ __launch_bounds__(256) void dec3_xt(const short* __restrict__ xh,
                                               const float* __restrict__ w,
                                               const float* __restrict__ bias,
                                               float* __restrict__ out, int NH) {
  int t = blockIdx.x * 256 + threadIdx.x;
  if (t >= NH * 128 * 128) return;
  const int px = t & 16383;
  const int nl = t >> 14;
  const int i = px >> 7, j = px & 127;
  const float b0 = bias[0];
  float a00 = b0, a01 = b0, a10 = b0, a11 = b0;
  const size_t base00 = (((size_t)nl * 130 + i + 1) * 130 + (j + 1)) * 32;
#pragma unroll
  for (int icg = 0; icg < 4; ++icg) {
    const short8 h00 = *(const short8*)(xh + base00 + icg * 8);
    const short8 h01 = *(const short8*)(xh + base00 + 32 + icg * 8);
    const short8 h10 = *(const short8*)(xh + base00 + 130 * 32 + icg * 8);
    const short8 h11 = *(const short8*)(xh + base00 + 130 * 32 + 32 + icg * 8);
#pragma unroll
    for (int kk = 0; kk < 8; ++kk) {
      const int ic = icg * 8 + kk;
      const float x00 = bf2f1(h00[kk]);
      const float x01 = bf2f1(h01[kk]);
      const float x10 = bf2f1(h10[kk]);
      const float x11 = bf2f1(h11[kk]);
      const float* wp = w + ic * 9;
      a00 = fmaf(x00, wp[4], a00);
      a01 = fmaf(x00, wp[5], fmaf(x01, wp[3], a01));
      a10 = fmaf(x00, wp[7], fmaf(x10, wp[1], a10));
      a11 = fmaf(x00, wp[8], fmaf(x01, wp[6], fmaf(x10, wp[2], fmaf(x11, wp[0], a11))));
    }
  }
  float* op = out + ((size_t)nl * 256 + 2 * i) * 256 + 2 * j;
  op[0] = a00; op[1] = a01; op[256] = a10; op[257] = a11;
}

// ---------------------------------------------------------------------------
extern "C" void kernel_launch(void* const* d_in, const int* in_sizes, int n_in,
                              void* d_out, int out_size, void* d_ws, size_t ws_size,
                              hipStream_t stream) {
  const float* x   = (const float*)d_in[0];
  const float* w1  = (const float*)d_in[1];
  const float* b1  = (const float*)d_in[2];
  const float* w2  = (const float*)d_in[3];
  const float* b2  = (const float*)d_in[4];
  const float* w3  = (const float*)d_in[5];
  const float* b3  = (const float*)d_in[6];
  const float* w4  = (const float*)d_in[7];
  const float* b4  = (const float*)d_in[8];
  const float* emb = (const float*)d_in[9];
  const float* dw1 = (const float*)d_in[10];
  const float* db1 = (const float*)d_in[11];
  const float* dw2 = (const float*)d_in[12];
  const float* db2 = (const float*)d_in[13];
  const float* dw3 = (const float*)d_in[14];
  const float* db3 = (const float*)d_in[15];
  float* outp = (float*)d_out;

  const int N = in_sizes[0] / (2 * 256 * 256);  // 64
  if (N & 1) return;
  const int NH = N / 2;

  // ---- arena (units: floats; 1 float = 2 shorts); R7-proven footprint ----
  const size_t sx3 = (size_t)N * 66 * 66 * 64;
  const size_t sx2 = (size_t)NH * 130 * 130 * 32;
  const size_t sx4 = (size_t)N * 34 * 34 * 128;
  const size_t se  = (size_t)N * 128 * 1024;
  const size_t sd1 = sx4;
  const size_t smalls = 512 + 18432 + 73728 + 147456 + 73728 + 18432 + 32768;
  const size_t need = (sx3 + sx4 + se + sd1 + smalls) * sizeof(float);
  if (ws_size < need) return;

  float* ws = (float*)d_ws;
  short* x3h = (short*)ws;                 short* x3l = x3h + sx3;   // enc split
  short* x2h = (short*)(ws + sx3);         short* x2l = x2h + sx2;
  short* x4h = (short*)(ws + sx3);         short* x4l = x4h + sx4;
  short* ech = (short*)(ws + sx3 + sx4);   short* ecl = ech + se;
  short* d1h = (short*)(ws + sx3 + sx4 + se);   // bf16-only decoder bufs
  short* d2h = (short*)ws;
  short* d3h = (short*)(ws + sx3);
  float* sm  = ws + sx3 + sx4 + se + sd1;
  float* nrm = sm;
  short* a2h = (short*)(sm + 512);                         short* a2l = a2h + 18432;
  short* a3h = (short*)(sm + 512 + 18432);                 short* a3l = a3h + 73728;
  short* a4h = (short*)(sm + 512 + 18432 + 73728);         short* a4l = a4h + 147456;
  short* ad1h = (short*)(sm + 512 + 18432 + 73728 + 147456);           // hi only
  short* ad2h = (short*)(sm + 512 + 18432 + 73728 + 147456 + 73728);   // hi only
  short* ebh = (short*)(sm + 512 + 18432 + 73728 + 147456 + 73728 + 18432); short* ebl = ebh + 32768;

  // ---- fused weight preps + VQ tables (R15) ----
  prep_all<<<1426, 256, 0, stream>>>(w2, w3, w4, dw1, dw2, emb,
                                     a2h, a2l, a3h, a3l, a4h, a4l,
                                     ad1h, ad2h, nrm, ebh, ebl);

  // ---- encoder (split-bf16, NP=2; A-LDS staged) ----
  ring_zero<<<(int)((NH * 516 * 32 + 255) / 256), 256, 0, stream>>>(x2h, x2l, NH, 130, 130, 32);
  ring_zero<<<(int)(((size_t)N * 260 * 64 + 255) / 256), 256, 0, stream>>>(x3h, x3l, N, 66, 66, 64);
  for (int half = 0; half < 2; ++half) {
    const int n0 = half * NH;
    conv1_xt<<<NH * 16384 / 256, 256, 0, stream>>>(
        x + (size_t)n0 * 2 * 65536, w1, b1, x2h, x2l, NH);
    conv_mfma_xt<32, 64, 64, 64, 2, 130, 130, 66, 66, 2>
        <<<NH * 32, 256, 0, stream>>>(x2h, x2l, a2h, a2l, b2,
                                      x3h + (size_t)n0 * 66 * 66 * 64,
                                      x3l + (size_t)n0 * 66 * 66 * 64);
  }
  ring_zero<<<(int)(((size_t)N * 132 * 128 + 255) / 256), 256, 0, stream>>>(x4h, x4l, N, 34, 34, 128);
  conv_mfma_xt<64, 128, 32, 32, 2, 66, 66, 34, 34, 2>
      <<<N * 8, 256, 0, stream>>>(x3h, x3l, a3h, a3l, b3, x4h, x4l);
  conv4_mfma<<<N * 8, 256, 0, stream>>>(x4h, x4l, a4h, a4l, b4, ech, ecl);

  // ---- VQ (split scoring, bf16 gather; R14 coalesced) ----
  ring_zero1<<<(int)(((size_t)N * 132 * 128 + 255) / 256), 256, 0, stream>>>(d1h, N, 34, 34, 128);
  vq_mfma<<<N * 16, 256, 0, stream>>>(ech, ecl, ebh, ebl, nrm, emb, d1h);

  // ---- decoder (plain bf16, NP=2; deconv1 A-LDS staged) ----
  ring_zero1<<<(int)(((size_t)N * 260 * 64 + 255) / 256), 256, 0, stream>>>(d2h, N, 66, 66, 64);
  deconv_bf16_xt<128, 64, 32, 32, 34, 34, 66, 66, 2, 1>
      <<<N * 8, 256, 0, stream>>>(d1h, ad1h, db1, d2h);
  ring_zero1<<<(int)((NH * 516 * 32 + 255) / 256), 256, 0, stream>>>(d3h, NH, 130, 130, 32);
  for (int half = 0; half < 2; ++half) {
    const int n0 = half * NH;
    deconv_bf16_xt<64, 32, 64, 64, 66, 66, 130, 130, 2, 0>
        <<<NH * 32, 256, 0, stream>>>(d2h + (size_t)n0 * 66 * 66 * 64,
                                      ad2h, db2, d3h);
    dec3_xt<<<NH * 16384 / 256, 256, 0, stream>>>(
        d3h, dw3, db3, outp + (size_t)n0 * 65536, NH);
  }
}

// Round 12
// 536.378 us; speedup vs baseline: 1.1662x; 1.0106x over previous
//
#include <hip/hip_runtime.h>

// ---------------------------------------------------------------------------
// VQ-VAE forward (NCHW). Round 21: generalize R20's 2-tap super-tap A staging
//  to conv_mfma_xt (conv2 x2, conv3).
//  R20 post-mortem: conv4 76.7->70.5us, MfmaUtil 34%, total 542 (best) --
//  barrier amortization confirmed (36->18 barriers, 96 MFMAs/barrier).
//  conv4 is now balanced (MFMA ~24us busy, A-LDS floor ~22us, HBM ~12us);
//  3-tap staging would need 96KB buffers -> 1 block/CU (proven loser).
//  Highest-EV: conv3 shares conv4's exact grid/shape/barrier structure;
//  conv2 has the same per-tap barrier. Change: conv_mfma_xt stages 2 A
//  tap-slices per buffer (pair prefetch, one barrier per 2 taps, odd-tail
//  guard for conv2's NSL=9). LDS conv3 32->64KB (2 blocks/CU unchanged),
//  conv2 16->32KB (4 blocks/CU unchanged). A bytes, B path, MFMA order
//  unchanged -> absmax 2.441e-4 exact. conv4(R20)/deconv/VQ/conv1/dec3
//  unchanged.
// ---------------------------------------------------------------------------

using short8  = __attribute__((ext_vector_type(8))) short;
using short4v = __attribute__((ext_vector_type(4))) short;
using floatx4 = __attribute__((ext_vector_type(4))) float;

__device__ inline unsigned short bf16rn(float f) {
  unsigned u = __float_as_uint(f);
  unsigned r = (u + 0x7fffu + ((u >> 16) & 1u)) >> 16;
  return (unsigned short)r;
}
__device__ inline float bf2f1(short h) {
  return __uint_as_float(((unsigned)(unsigned short)h) << 16);
}

// ---- deconv tap tables: entry e -> (ky,kx) weight tap
__device__ const int DKY[9]  = {1, 1, 1, 2, 0, 2, 2, 0, 0};
__device__ const int DKX[9]  = {1, 2, 0, 1, 1, 2, 0, 2, 0};

// ---------------- ring zero (split pair) ----------------------------------
__global__ __launch_bounds__(256) void ring_zero(short* __restrict__ h,
                                                 short* __restrict__ l,
                                                 int nimg, int PH, int PW, int C) {
  const int RC = (2 * PW + 2 * (PH - 2)) * C;
  int t = blockIdx.x * 256 + threadIdx.x;
  if (t >= nimg * RC) return;
  const int nl = t / RC;
  int rem = t - nl * RC;
  const int p = rem / C;
  const int ch = rem - p * C;
  int r, c;
  if (p < 2 * PW) {
    r = (p < PW) ? 0 : PH - 1;
    c = (p < PW) ? p : p - PW;
  } else {
    int q = p - 2 * PW;
    if (q < PH - 2) { r = 1 + q; c = 0; }
    else { r = 1 + q - (PH - 2); c = PW - 1; }
  }
  const size_t a = (((size_t)nl * PH + r) * PW + c) * C + ch;
  h[a] = 0; l[a] = 0;
}

// ---------------- ring zero (single buffer) -------------------------------
__global__ __launch_bounds__(256) void ring_zero1(short* __restrict__ h,
                                                  int nimg, int PH, int PW, int C) {
  const int RC = (2 * PW + 2 * (PH - 2)) * C;
  int t = blockIdx.x * 256 + threadIdx.x;
  if (t >= nimg * RC) return;
  const int nl = t / RC;
  int rem = t - nl * RC;
  const int p = rem / C;
  const int ch = rem - p * C;
  int r, c;
  if (p < 2 * PW) {
    r = (p < PW) ? 0 : PH - 1;
    c = (p < PW) ? p : p - PW;
  } else {
    int q = p - 2 * PW;
    if (q < PH - 2) { r = 1 + q; c = 0; }
    else { r = 1 + q - (PH - 2); c = PW - 1; }
  }
  h[(((size_t)nl * PH + r) * PW + c) * C + ch] = 0;
}

// ---------------- conv1: fp32 direct, writes xt [nh][130][130][32] --------
__global__ __launch_bounds__(256) void conv1_xt(const float* __restrict__ x,
                                                const float* __restrict__ w,
                                                const float* __restrict__ bias,
                                                short* __restrict__ oh,
                                                short* __restrict__ ol, int NH) {
  int t = blockIdx.x * 256 + threadIdx.x;
  if (t >= NH * 128 * 128) return;
  const int px = t & 16383;
  const int n  = t >> 14;
  const int r = px >> 7, c = px & 127;
  const int ih0 = 2 * r - 1, iw0 = 2 * c - 1;
  float acc[32];
#pragma unroll
  for (int o = 0; o < 32; ++o) acc[o] = bias[o];
  const float* ip = x + (size_t)n * 2 * 65536;
#pragma unroll
  for (int ic = 0; ic < 2; ++ic, ip += 65536) {
    float v[9];
#pragma unroll
    for (int kh = 0; kh < 3; ++kh) {
      const int ih = ih0 + kh;
#pragma unroll
      for (int kw = 0; kw < 3; ++kw) {
        const int iw = iw0 + kw;
        const bool ok = (ih >= 0) && (ih < 256) && (iw < 256) && (iw >= 0);
        v[kh * 3 + kw] = ok ? ip[ih * 256 + iw] : 0.f;
      }
    }
#pragma unroll
    for (int o = 0; o < 32; ++o) {
      float s = acc[o];
#pragma unroll
      for (int k = 0; k < 9; ++k) s = fmaf(v[k], w[(o * 2 + ic) * 9 + k], s);
      acc[o] = s;
    }
  }
  const size_t base = (((size_t)n * 130 + r + 1) * 130 + (c + 1)) * 32;
  short8 vh[4], vl[4];
#pragma unroll
  for (int g = 0; g < 4; ++g) {
#pragma unroll
    for (int kk = 0; kk < 8; ++kk) {
      const float rv = fmaxf(acc[g * 8 + kk], 0.f);
      const unsigned short hh = bf16rn(rv);
      vh[g][kk] = (short)hh;
      vl[g][kk] = (short)bf16rn(rv - __uint_as_float((unsigned)hh << 16));
    }
    *(short8*)(oh + base + g * 8) = vh[g];
    *(short8*)(ol + base + g * 8) = vl[g];
  }
}

// ---------------- fused weight/table prep (R15) ---------------------------
template<int CIN, int COUT>
__device__ inline void wprep_conv_body(int t, const float* __restrict__ w,
                                       short* __restrict__ hi,
                                       short* __restrict__ lo) {
  constexpr int MT = COUT / 16;
  const int j = t & 7;
  const int lane = (t >> 3) & 63;
  const int g = t >> 9;
  const int mt = g % MT;
  const int s = g / MT;
  const int icb = s / 9, tap = s - icb * 9;
  const int kh = tap / 3, kw = tap - kh * 3;
  const int m = mt * 16 + (lane & 15);
  const int ic = icb * 32 + ((lane >> 4) << 3) + j;
  const float v = w[((m * CIN + ic) * 3 + kh) * 3 + kw];
  const unsigned short h = bf16rn(v);
  hi[t] = (short)h;
  lo[t] = (short)bf16rn(v - __uint_as_float((unsigned)h << 16));
}

template<int CIN, int COUT>
__device__ inline void wprep_dec_body(int t, const float* __restrict__ w,
                                      short* __restrict__ hi) {
  constexpr int MT = COUT / 16, ICB = CIN / 32;
  const int j = t & 7;
  const int lane = (t >> 3) & 63;
  const int g = t >> 9;
  const int mt = g % MT;
  const int u = g / MT;
  const int icb = u % ICB;
  const int e = u / ICB;
  const int ky = DKY[e], kx = DKX[e];
  const int m = mt * 16 + (lane & 15);
  const int ic = icb * 32 + ((lane >> 4) << 3) + j;
  hi[t] = (short)bf16rn(w[((ic * COUT + m) * 3 + ky) * 3 + kx]);
}

__global__ __launch_bounds__(256) void prep_all(
    const float* __restrict__ w2, const float* __restrict__ w3,
    const float* __restrict__ w4, const float* __restrict__ dw1,
    const float* __restrict__ dw2, const float* __restrict__ emb,
    short* __restrict__ a2h, short* __restrict__ a2l,
    short* __restrict__ a3h, short* __restrict__ a3l,
    short* __restrict__ a4h, short* __restrict__ a4l,
    short* __restrict__ ad1h, short* __restrict__ ad2h,
    float* __restrict__ nrm, short* __restrict__ ebh,
    short* __restrict__ ebl) {
  const int bb = blockIdx.x;
  const int tid = threadIdx.x;
  if (bb < 72) {
    wprep_conv_body<32, 64>(bb * 256 + tid, w2, a2h, a2l);
  } else if (bb < 360) {
    wprep_conv_body<64, 128>((bb - 72) * 256 + tid, w3, a3h, a3l);
  } else if (bb < 936) {
    wprep_conv_body<128, 128>((bb - 360) * 256 + tid, w4, a4h, a4l);
  } else if (bb < 1224) {
    wprep_dec_body<128, 64>((bb - 936) * 256 + tid, dw1, ad1h);
  } else if (bb < 1296) {
    wprep_dec_body<64, 32>((bb - 1224) * 256 + tid, dw2, ad2h);
  } else if (bb < 1424) {
    const int t = (bb - 1296) * 256 + tid;   // < 32768
    const int j  = t & 7;
    const int l  = (t >> 3) & 63;
    const int kk = (t >> 9) & 1;
    const int ct = t >> 10;
    const int code = ct * 16 + (l & 15);
    const int k = kk * 32 + ((l >> 4) << 3) + j;
    const float v = emb[code * 64 + k];
    const unsigned short h = bf16rn(v);
    ebh[t] = (short)h;
    ebl[t] = (short)bf16rn(v - __uint_as_float((unsigned)h << 16));
  } else {
    const int jj = (bb - 1424) * 256 + tid;
    if (jj < 512) {
      float s = 0.f;
      const float* e = emb + jj * 64;
#pragma unroll
      for (int k = 0; k < 64; ++k) s = fmaf(e[k], e[k], s);
      nrm[jj] = s;
    }
  }
}

// ------- generic strided conv MFMA (split xt -> split xt), NP tiles -------
// R21: A staged 2 tap-slices per LDS buffer, pair prefetch, one barrier
// per 2 taps (R20's proven conv4 pattern generalized; odd-NSL tail guarded).
template<int CIN, int COUT, int OH, int OW, int S, int PHI, int PWI, int PHO, int PWO, int NP>
__global__ __launch_bounds__(256) void conv_mfma_xt(
    const short* __restrict__ xih, const short* __restrict__ xil,
    const short* __restrict__ ah,  const short* __restrict__ al,
    const float* __restrict__ bias,
    short* __restrict__ xoh, short* __restrict__ xol) {
  constexpr int MT = COUT / 16, ICB = CIN / 32;
  constexpr int PXB = 64 * NP, TPB = OH * OW / PXB;
  constexpr int NSL = ICB * 9;            // total A slices
  constexpr int NST = (NSL + 1) / 2;      // super-taps (2 slices each)
  constexpr int CH  = MT * 64;            // short8 chunks per slice
  constexpr int C2  = 2 * CH;             // chunks per buffer
  constexpr int CPT = (C2 + 255) / 256;   // chunks per thread
  __shared__ short ash[2][C2 * 8];
  __shared__ short asl2[2][C2 * 8];
  const int b = blockIdx.x;
  const int n = b / TPB, pt = b % TPB;
  const int tid = threadIdx.x;
  const int lane = tid & 63, wave = tid >> 6;
  const int quad = lane >> 4;
  int rr[NP], cc[NP];
  size_t bbase[NP];
#pragma unroll
  for (int p = 0; p < NP; ++p) {
    const int pl = pt * PXB + wave * (16 * NP) + p * 16 + (lane & 15);
    rr[p] = pl / OW; cc[p] = pl % OW;
    bbase[p] = (((size_t)n * PHI + S * rr[p]) * PWI + S * cc[p]) * CIN + quad * 8;
  }

  floatx4 acc[MT][NP];
#pragma unroll
  for (int mt = 0; mt < MT; ++mt)
#pragma unroll
    for (int p = 0; p < NP; ++p) acc[mt][p] = (floatx4){0.f, 0.f, 0.f, 0.f};

  const short8* __restrict__ ah8 = (const short8*)ah;
  const short8* __restrict__ al8 = (const short8*)al;

  // prologue: stage slices 0..1 into buffer 0 (guard total-chunk bound)
  short8 ra[CPT], rl[CPT];
#pragma unroll
  for (int c = 0; c < CPT; ++c) {
    const int idx = tid + c * 256;
    if (idx < C2 && idx < NSL * CH) { ra[c] = ah8[idx]; rl[c] = al8[idx]; }
  }
#pragma unroll
  for (int c = 0; c < CPT; ++c) {
    const int idx = tid + c * 256;
    if (idx < C2 && idx < NSL * CH) {
      *(short8*)(ash[0] + idx * 8) = ra[c];
      *(short8*)(asl2[0] + idx * 8) = rl[c];
    }
  }
  __syncthreads();

  for (int st = 0; st < NST; ++st) {
    // prefetch next super-tap's slices into regs
    if (st + 1 < NST) {
      const int base = (st + 1) * C2;
#pragma unroll
      for (int c = 0; c < CPT; ++c) {
        const int idx = tid + c * 256;
        if (idx < C2 && base + idx < NSL * CH) {
          ra[c] = ah8[base + idx]; rl[c] = al8[base + idx];
        }
      }
    }
#pragma unroll
    for (int t2 = 0; t2 < 2; ++t2) {
      const int s = st * 2 + t2;
      if (s < NSL) {
        const int icb = s / 9, tap = s - icb * 9;
        const int kh = tap / 3, kw = tap - kh * 3;
        short8 bh[NP], bl[NP];
#pragma unroll
        for (int p = 0; p < NP; ++p) {
          const size_t be = bbase[p] + (size_t)(kh * PWI + kw) * CIN + icb * 32;
          bh[p] = *(const short8*)(xih + be);
          bl[p] = *(const short8*)(xil + be);
        }
        const short8* __restrict__ a8h = (const short8*)ash[st & 1] + t2 * CH;
        const short8* __restrict__ a8l = (const short8*)asl2[st & 1] + t2 * CH;
#pragma unroll
        for (int mt = 0; mt < MT; ++mt) {
          const short8 wh = a8h[mt * 64 + lane];
          const short8 wl = a8l[mt * 64 + lane];
#pragma unroll
          for (int p = 0; p < NP; ++p) {
            acc[mt][p] = __builtin_amdgcn_mfma_f32_16x16x32_bf16(wh, bh[p], acc[mt][p], 0, 0, 0);
            acc[mt][p] = __builtin_amdgcn_mfma_f32_16x16x32_bf16(wh, bl[p], acc[mt][p], 0, 0, 0);
            acc[mt][p] = __builtin_amdgcn_mfma_f32_16x16x32_bf16(wl, bh[p], acc[mt][p], 0, 0, 0);
          }
        }
      }
    }
    if (st + 1 < NST) {
      const int nb = (st + 1) & 1;
      const int base = (st + 1) * C2;
#pragma unroll
      for (int c = 0; c < CPT; ++c) {
        const int idx = tid + c * 256;
        if (idx < C2 && base + idx < NSL * CH) {
          *(short8*)(ash[nb] + idx * 8) = ra[c];
          *(short8*)(asl2[nb] + idx * 8) = rl[c];
        }
      }
      __syncthreads();
    }
  }
#pragma unroll
  for (int p = 0; p < NP; ++p) {
    const size_t ob = (((size_t)n * PHO + rr[p] + 1) * PWO + (cc[p] + 1)) * COUT + quad * 4;
#pragma unroll
    for (int mt = 0; mt < MT; ++mt) {
      short4v sh, sl;
#pragma unroll
      for (int q = 0; q < 4; ++q) {
        const float v = fmaxf(acc[mt][p][q] + bias[mt * 16 + quad * 4 + q], 0.f);
        const unsigned short hh = bf16rn(v);
        sh[q] = (short)hh;
        sl[q] = (short)bf16rn(v - __uint_as_float((unsigned)hh << 16));
      }
      *(short4v*)(xoh + ob + mt * 16) = sh;
      *(short4v*)(xol + ob + mt * 16) = sl;
    }
  }
}

// ---- fused transposed conv, plain bf16, NP pixel-tiles per wave ----------
// R15: ASTG=1 stages the per-icb A group (9 e-slices) in LDS, double-buffered.
template<int CIN, int COUT, int IH, int IW, int PHI, int PWI, int PHO, int PWO, int NP, int ASTG>
__global__ __launch_bounds__(256) void deconv_bf16_xt(
    const short* __restrict__ xih, const short* __restrict__ ah,
    const float* __restrict__ bias, short* __restrict__ xoh) {
  constexpr int MT = COUT / 16, ICB = CIN / 32;
  constexpr int PXB = 64 * NP, TPB = IH * IW / PXB;
  constexpr int CHI = 9 * MT * 64;               // chunks per icb A-group
  constexpr int CPT = (CHI + 255) / 256;
  constexpr int PHE[9] = {0, 1, 1, 2, 2, 3, 3, 3, 3};
  constexpr int DE[9]  = {0, 0, 1, 0, 2, 0, 1, 2, 3};
  __shared__ short ash[ASTG ? 2 * CHI * 8 : 1];
  const int b = blockIdx.x;
  const int n = b / TPB, pt = b % TPB;
  const int tid = threadIdx.x;
  const int lane = tid & 63, wave = tid >> 6;
  const int quad = lane >> 4;
  int ii[NP], jj[NP];
  size_t p00[NP];
#pragma unroll
  for (int p = 0; p < NP; ++p) {
    const int pl = pt * PXB + wave * (16 * NP) + p * 16 + (lane & 15);
    ii[p] = pl / IW; jj[p] = pl % IW;
    p00[p] = (((size_t)n * PHI + (ii[p] + 1)) * PWI + (jj[p] + 1)) * CIN + quad * 8;
  }

  floatx4 acc[4][MT][NP];
#pragma unroll
  for (int ph = 0; ph < 4; ++ph)
#pragma unroll
    for (int mt = 0; mt < MT; ++mt)
#pragma unroll
      for (int p = 0; p < NP; ++p) acc[ph][mt][p] = (floatx4){0.f, 0.f, 0.f, 0.f};

  const short8* __restrict__ ah8 = (const short8*)ah;

  short8 ra[ASTG ? CPT : 1];
  if constexpr (ASTG) {
    // prologue: stage icb0's 9 e-slices into buffer 0
#pragma unroll
    for (int c = 0; c < CPT; ++c) {
      const int idx = tid + c * 256;
      if (idx < CHI) {
        const int e = idx / (MT * 64);
        const int rem = idx - e * (MT * 64);
        ra[c] = ah8[(e * ICB + 0) * (MT * 64) + rem];
      }
    }
#pragma unroll
    for (int c = 0; c < CPT; ++c) {
      const int idx = tid + c * 256;
      if (idx < CHI) *(short8*)(ash + idx * 8) = ra[c];
    }
    __syncthreads();
  }

  for (int icb = 0; icb < ICB; ++icb) {
    short8 bh[NP][4];
#pragma unroll
    for (int p = 0; p < NP; ++p)
#pragma unroll
      for (int d = 0; d < 4; ++d)
        bh[p][d] = *(const short8*)(xih + p00[p] +
                                    (size_t)((d >> 1) * PWI + (d & 1)) * CIN + icb * 32);
    if constexpr (ASTG) {
      if (icb + 1 < ICB) {
#pragma unroll
        for (int c = 0; c < CPT; ++c) {
          const int idx = tid + c * 256;
          if (idx < CHI) {
            const int e = idx / (MT * 64);
            const int rem = idx - e * (MT * 64);
            ra[c] = ah8[(e * ICB + icb + 1) * (MT * 64) + rem];
          }
        }
      }
    }
#pragma unroll
    for (int e = 0; e < 9; ++e) {
      const int ph = PHE[e], d = DE[e];
#pragma unroll
      for (int mt = 0; mt < MT; ++mt) {
        short8 wh;
        if constexpr (ASTG)
          wh = ((const short8*)(ash + (size_t)(icb & 1) * CHI * 8))[(e * MT + mt) * 64 + lane];
        else
          wh = ah8[((e * ICB + icb) * MT + mt) * 64 + lane];
#pragma unroll
        for (int p = 0; p < NP; ++p)
          acc[ph][mt][p] = __builtin_amdgcn_mfma_f32_16x16x32_bf16(
              wh, bh[p][d], acc[ph][mt][p], 0, 0, 0);
      }
    }
    if constexpr (ASTG) {
      if (icb + 1 < ICB) {
        const size_t nb = (size_t)((icb + 1) & 1) * CHI * 8;
#pragma unroll
        for (int c = 0; c < CPT; ++c) {
          const int idx = tid + c * 256;
          if (idx < CHI) *(short8*)(ash + nb + idx * 8) = ra[c];
        }
        __syncthreads();
      }
    }
  }
#pragma unroll
  for (int p = 0; p < NP; ++p)
#pragma unroll
    for (int ph = 0; ph < 4; ++ph) {
      const int oy = 2 * ii[p] + (ph >> 1), ox = 2 * jj[p] + (ph & 1);
      const size_t ob = (((size_t)n * PHO + oy + 1) * PWO + (ox + 1)) * COUT + quad * 4;
#pragma unroll
      for (int mt = 0; mt < MT; ++mt) {
        short4v sh;
#pragma unroll
        for (int q = 0; q < 4; ++q)
          sh[q] = (short)bf16rn(fmaxf(acc[ph][mt][p][q] + bias[mt * 16 + quad * 4 + q], 0.f));
        *(short4v*)(xoh + ob + mt * 16) = sh;
      }
    }
}

// ---------------- conv4 MFMA (R20): A staged 2 taps/buffer, 18 barriers ---
__global__ __launch_bounds__(256) void conv4_mfma(
    const short* __restrict__ xthi, const short* __restrict__ xtlo,
    const short* __restrict__ ahi,  const short* __restrict__ alo,
    const float* __restrict__ bias,
    short* __restrict__ ench, short* __restrict__ encl) {
  __shared__ short ash[2][8192];        // 2 x 16384 B (A hi, two tap slices)
  __shared__ short asl[2][8192];        // 2 x 16384 B (A lo)
  const int b    = blockIdx.x;          // N*8 blocks, 128 pixels each
  const int n    = b >> 3;
  const int pt   = b & 7;
  const int tid  = threadIdx.x;
  const int lane = tid & 63;
  const int wave = tid >> 6;
  const int kq   = lane >> 4;
  int pl[2];
  size_t bbase[2];
#pragma unroll
  for (int p = 0; p < 2; ++p) {
    pl[p] = pt * 128 + wave * 32 + p * 16 + (lane & 15);
    const int r = pl[p] >> 5, c = pl[p] & 31;
    bbase[p] = (((size_t)n * 34 + r) * 34 + c) * 128 + kq * 8;
  }

  floatx4 acc[8][2];
#pragma unroll
  for (int mt = 0; mt < 8; ++mt)
#pragma unroll
    for (int p = 0; p < 2; ++p) acc[mt][p] = (floatx4){0.f, 0.f, 0.f, 0.f};

  const short8* __restrict__ ah8 = (const short8*)ahi;
  const short8* __restrict__ al8 = (const short8*)alo;

  // A prologue: stage tap-slices 0,1 (1024 chunks each of hi/lo) into buf 0
  short8 rah[4], ral[4];
#pragma unroll
  for (int c = 0; c < 4; ++c) {
    rah[c] = ah8[tid + c * 256];
    ral[c] = al8[tid + c * 256];
  }
#pragma unroll
  for (int c = 0; c < 4; ++c) {
    *(short8*)(ash[0] + (tid + c * 256) * 8) = rah[c];
    *(short8*)(asl[0] + (tid + c * 256) * 8) = ral[c];
  }
  __syncthreads();

  for (int st = 0; st < 18; ++st) {
    // prefetch next super-tap's 2 A slices into regs
    if (st < 17) {
      const int nb = (st + 1) * 1024;
#pragma unroll
      for (int c = 0; c < 4; ++c) {
        rah[c] = ah8[nb + tid + c * 256];
        ral[c] = al8[nb + tid + c * 256];
      }
    }
#pragma unroll
    for (int t2 = 0; t2 < 2; ++t2) {
      const int s = st * 2 + t2;
      const int icb = s / 9, tap = s - icb * 9;
      const int kh = tap / 3, kw = tap - kh * 3;
      const short8* __restrict__ a8h = (const short8*)ash[st & 1] + t2 * 512;
      const short8* __restrict__ a8l = (const short8*)asl[st & 1] + t2 * 512;
      short8 bh[2], bl[2];
#pragma unroll
      for (int p = 0; p < 2; ++p) {
        const size_t be = bbase[p] + (size_t)(kh * 34 + kw) * 128 + icb * 32;
        bh[p] = *(const short8*)(xthi + be);
        bl[p] = *(const short8*)(xtlo + be);
      }
#pragma unroll
      for (int mt = 0; mt < 8; ++mt) {
        const short8 ah = a8h[mt * 64 + lane];
        const short8 al = a8l[mt * 64 + lane];
#pragma unroll
        for (int p = 0; p < 2; ++p) {
          acc[mt][p] = __builtin_amdgcn_mfma_f32_16x16x32_bf16(ah, bh[p], acc[mt][p], 0, 0, 0);
          acc[mt][p] = __builtin_amdgcn_mfma_f32_16x16x32_bf16(ah, bl[p], acc[mt][p], 0, 0, 0);
          acc[mt][p] = __builtin_amdgcn_mfma_f32_16x16x32_bf16(al, bh[p], acc[mt][p], 0, 0, 0);
        }
      }
    }
    if (st < 17) {
      const int nbuf = (st + 1) & 1;
#pragma unroll
      for (int c = 0; c < 4; ++c) {
        *(short8*)(ash[nbuf] + (tid + c * 256) * 8) = rah[c];
        *(short8*)(asl[nbuf] + (tid + c * 256) * 8) = ral[c];
      }
      __syncthreads();
    }
  }
#pragma unroll
  for (int p = 0; p < 2; ++p) {
    const size_t obase = (size_t)n * 128 * 1024 + pl[p];
#pragma unroll
    for (int mt = 0; mt < 8; ++mt) {
#pragma unroll
      for (int q = 0; q < 4; ++q) {
        const int cout = mt * 16 + kq * 4 + q;
        const float rr = fmaxf(acc[mt][p][q] + bias[cout], 0.f);
        const unsigned short h = bf16rn(rr);
        const size_t oi = obase + (size_t)cout * 1024;
        ench[oi] = (short)h;
        encl[oi] = (short)bf16rn(rr - __uint_as_float((unsigned)h << 16));
      }
    }
  }
}

// ---- vq_mfma (R14): block = (n, one 64-px block, all 128 ch) -------------
__global__ __launch_bounds__(256) void vq_mfma(
    const short* __restrict__ fhi, const short* __restrict__ flo,
    const short* __restrict__ ebh, const short* __restrict__ ebl,
    const float* __restrict__ nrm, const float* __restrict__ emb,
    short* __restrict__ d1h) {
  __shared__ int sidx[128];
  const int lane = threadIdx.x & 63;
  const int wave = threadIdx.x >> 6;
  const int n  = blockIdx.x >> 4;
  const int pb = blockIdx.x & 15;

  short8 ah0[2], ah1[2], al0[2], al1[2];
#pragma unroll
  for (int g = 0; g < 2; ++g) {
    const int ch = wave * 32 + g * 16 + (lane & 15);
    const size_t abase = (((size_t)(n * 128 + ch)) * 16 + pb) * 64 + ((lane >> 4) << 3);
    ah0[g] = *(const short8*)(fhi + abase);
    ah1[g] = *(const short8*)(fhi + abase + 32);
    al0[g] = *(const short8*)(flo + abase);
    al1[g] = *(const short8*)(flo + abase + 32);
  }

  float bestv[2][4];
  int   besti[2][4];
#pragma unroll
  for (int g = 0; g < 2; ++g)
#pragma unroll
    for (int q = 0; q < 4; ++q) { bestv[g][q] = 3.4e38f; besti[g][q] = 0; }

  const short8* __restrict__ ebh8 = (const short8*)ebh;
  const short8* __restrict__ ebl8 = (const short8*)ebl;
  for (int ct = 0; ct < 32; ++ct) {
    const int f0 = (ct * 2) * 64 + lane;
    const short8 b0h = ebh8[f0];
    const short8 b1h = ebh8[f0 + 64];
    const short8 b0l = ebl8[f0];
    const short8 b1l = ebl8[f0 + 64];
    const int code = ct * 16 + (lane & 15);
    const float nn = nrm[code];
#pragma unroll
    for (int g = 0; g < 2; ++g) {
      floatx4 acc = {0.f, 0.f, 0.f, 0.f};
      acc = __builtin_amdgcn_mfma_f32_16x16x32_bf16(ah0[g], b0h, acc, 0, 0, 0);
      acc = __builtin_amdgcn_mfma_f32_16x16x32_bf16(ah1[g], b1h, acc, 0, 0, 0);
      acc = __builtin_amdgcn_mfma_f32_16x16x32_bf16(ah0[g], b0l, acc, 0, 0, 0);
      acc = __builtin_amdgcn_mfma_f32_16x16x32_bf16(ah1[g], b1l, acc, 0, 0, 0);
      acc = __builtin_amdgcn_mfma_f32_16x16x32_bf16(al0[g], b0h, acc, 0, 0, 0);
      acc = __builtin_amdgcn_mfma_f32_16x16x32_bf16(al1[g], b1h, acc, 0, 0, 0);
#pragma unroll
      for (int q = 0; q < 4; ++q) {
        const float sc = nn - 2.f * acc[q];
        if (sc < bestv[g][q]) { bestv[g][q] = sc; besti[g][q] = code; }
      }
    }
  }
#pragma unroll
  for (int off = 1; off < 16; off <<= 1) {
#pragma unroll
    for (int g = 0; g < 2; ++g)
#pragma unroll
      for (int q = 0; q < 4; ++q) {
        const float ov = __shfl_xor(bestv[g][q], off, 64);
        const int   oi = __shfl_xor(besti[g][q], off, 64);
        if (ov < bestv[g][q] || (ov == bestv[g][q] && oi < besti[g][q])) {
          bestv[g][q] = ov; besti[g][q] = oi;
        }
      }
  }
  if ((lane & 15) == 0) {
#pragma unroll
    for (int g = 0; g < 2; ++g)
#pragma unroll
      for (int q = 0; q < 4; ++q)
        sidx[wave * 32 + g * 16 + (lane >> 4) * 4 + q] = besti[g][q];
  }
  __syncthreads();
  const int chg = (threadIdx.x & 15) * 8;
  int gi8[8];
#pragma unroll
  for (int k = 0; k < 8; ++k) gi8[k] = sidx[chg + k];
#pragma unroll
  for (int pxg = 0; pxg < 4; ++pxg) {
    const int p = pxg * 16 + (threadIdx.x >> 4);   // 0..63
    const int pix = pb * 64 + p;
    const int r = pix >> 5, c = pix & 31;
    short8 v;
#pragma unroll
    for (int k = 0; k < 8; ++k)
      v[k] = (short)bf16rn(emb[(size_t)gi8[k] * 64 + p]);
    *(short8*)(d1h + (((size_t)n * 34 + r + 1) * 34 + (c + 1)) * 128 + chg) = v;
  }
}

// ---------------- dec3: fp32 direct from single-bf16 xt input -------------
__global__ __launch_bounds__(256) void dec3_xt(const short* __restrict__ xh,
                                               const float* __restrict__ w,
                                               const float* __restrict__ bias,
                                               float* __restrict__ out, int NH) {
  int t = blockIdx.x * 256 + threadIdx.x;
  if (t >= NH * 128 * 128) return;
  const int px = t & 16383;
  const int nl = t >> 14;
  const int i = px >> 7, j = px & 127;
  const float b0 = bias[0];
  float a00 = b0, a01 = b0, a10 = b0, a11 = b0;
  const size_t base00 = (((size_t)nl * 130 + i + 1) * 130 + (j + 1)) * 32;
#pragma unroll
  for (int icg = 0; icg < 4; ++icg) {
    const short8 h00 = *(const short8*)(xh + base00 + icg * 8);
    const short8 h01 = *(const short8*)(xh + base00 + 32 + icg * 8);
    const short8 h10 = *(const short8*)(xh + base00 + 130 * 32 + icg * 8);
    const short8 h11 = *(const short8*)(xh + base00 + 130 * 32 + 32 + icg * 8);
#pragma unroll
    for (int kk = 0; kk < 8; ++kk) {
      const int ic = icg * 8 + kk;
      const float x00 = bf2f1(h00[kk]);
      const float x01 = bf2f1(h01[kk]);
      const float x10 = bf2f1(h10[kk]);
      const float x11 = bf2f1(h11[kk]);
      const float* wp = w + ic * 9;
      a00 = fmaf(x00, wp[4], a00);
      a01 = fmaf(x00, wp[5], fmaf(x01, wp[3], a01));
      a10 = fmaf(x00, wp[7], fmaf(x10, wp[1], a10));
      a11 = fmaf(x00, wp[8], fmaf(x01, wp[6], fmaf(x10, wp[2], fmaf(x11, wp[0], a11))));
    }
  }
  float* op = out + ((size_t)nl * 256 + 2 * i) * 256 + 2 * j;
  op[0] = a00; op[1] = a01; op[256] = a10; op[257] = a11;
}

// ---------------------------------------------------------------------------
extern "C" void kernel_launch(void* const* d_in, const int* in_sizes, int n_in,
                              void* d_out, int out_size, void* d_ws, size_t ws_size,
                              hipStream_t stream) {
  const float* x   = (const float*)d_in[0];
  const float* w1  = (const float*)d_in[1];
  const float* b1  = (const float*)d_in[2];
  const float* w2  = (const float*)d_in[3];
  const float* b2  = (const float*)d_in[4];
  const float* w3  = (const float*)d_in[5];
  const float* b3  = (const float*)d_in[6];
  const float* w4  = (const float*)d_in[7];
  const float* b4  = (const float*)d_in[8];
  const float* emb = (const float*)d_in[9];
  const float* dw1 = (const float*)d_in[10];
  const float* db1 = (const float*)d_in[11];
  const float* dw2 = (const float*)d_in[12];
  const float* db2 = (const float*)d_in[13];
  const float* dw3 = (const float*)d_in[14];
  const float* db3 = (const float*)d_in[15];
  float* outp = (float*)d_out;

  const int N = in_sizes[0] / (2 * 256 * 256);  // 64
  if (N & 1) return;
  const int NH = N / 2;

  // ---- arena (units: floats; 1 float = 2 shorts); R7-proven footprint ----
  const size_t sx3 = (size_t)N * 66 * 66 * 64;
  const size_t sx2 = (size_t)NH * 130 * 130 * 32;
  const size_t sx4 = (size_t)N * 34 * 34 * 128;
  const size_t se  = (size_t)N * 128 * 1024;
  const size_t sd1 = sx4;
  const size_t smalls = 512 + 18432 + 73728 + 147456 + 73728 + 18432 + 32768;
  const size_t need = (sx3 + sx4 + se + sd1 + smalls) * sizeof(float);
  if (ws_size < need) return;

  float* ws = (float*)d_ws;
  short* x3h = (short*)ws;                 short* x3l = x3h + sx3;   // enc split
  short* x2h = (short*)(ws + sx3);         short* x2l = x2h + sx2;
  short* x4h = (short*)(ws + sx3);         short* x4l = x4h + sx4;
  short* ech = (short*)(ws + sx3 + sx4);   short* ecl = ech + se;
  short* d1h = (short*)(ws + sx3 + sx4 + se);   // bf16-only decoder bufs
  short* d2h = (short*)ws;
  short* d3h = (short*)(ws + sx3);
  float* sm  = ws + sx3 + sx4 + se + sd1;
  float* nrm = sm;
  short* a2h = (short*)(sm + 512);                         short* a2l = a2h + 18432;
  short* a3h = (short*)(sm + 512 + 18432);                 short* a3l = a3h + 73728;
  short* a4h = (short*)(sm + 512 + 18432 + 73728);         short* a4l = a4h + 147456;
  short* ad1h = (short*)(sm + 512 + 18432 + 73728 + 147456);           // hi only
  short* ad2h = (short*)(sm + 512 + 18432 + 73728 + 147456 + 73728);   // hi only
  short* ebh = (short*)(sm + 512 + 18432 + 73728 + 147456 + 73728 + 18432); short* ebl = ebh + 32768;

  // ---- fused weight preps + VQ tables (R15) ----
  prep_all<<<1426, 256, 0, stream>>>(w2, w3, w4, dw1, dw2, emb,
                                     a2h, a2l, a3h, a3l, a4h, a4l,
                                     ad1h, ad2h, nrm, ebh, ebl);

  // ---- encoder (split-bf16, NP=2; A-LDS 2-tap staged) ----
  ring_zero<<<(int)((NH * 516 * 32 + 255) / 256), 256, 0, stream>>>(x2h, x2l, NH, 130, 130, 32);
  ring_zero<<<(int)(((size_t)N * 260 * 64 + 255) / 256), 256, 0, stream>>>(x3h, x3l, N, 66, 66, 64);
  for (int half = 0; half < 2; ++half) {
    const int n0 = half * NH;
    conv1_xt<<<NH * 16384 / 256, 256, 0, stream>>>(
        x + (size_t)n0 * 2 * 65536, w1, b1, x2h, x2l, NH);
    conv_mfma_xt<32, 64, 64, 64, 2, 130, 130, 66, 66, 2>
        <<<NH * 32, 256, 0, stream>>>(x2h, x2l, a2h, a2l, b2,
                                      x3h + (size_t)n0 * 66 * 66 * 64,
                                      x3l + (size_t)n0 * 66 * 66 * 64);
  }
  ring_zero<<<(int)(((size_t)N * 132 * 128 + 255) / 256), 256, 0, stream>>>(x4h, x4l, N, 34, 34, 128);
  conv_mfma_xt<64, 128, 32, 32, 2, 66, 66, 34, 34, 2>
      <<<N * 8, 256, 0, stream>>>(x3h, x3l, a3h, a3l, b3, x4h, x4l);
  conv4_mfma<<<N * 8, 256, 0, stream>>>(x4h, x4l, a4h, a4l, b4, ech, ecl);

  // ---- VQ (split scoring, bf16 gather; R14 coalesced) ----
  ring_zero1<<<(int)(((size_t)N * 132 * 128 + 255) / 256), 256, 0, stream>>>(d1h, N, 34, 34, 128);
  vq_mfma<<<N * 16, 256, 0, stream>>>(ech, ecl, ebh, ebl, nrm, emb, d1h);

  // ---- decoder (plain bf16, NP=2; deconv1 A-LDS staged) ----
  ring_zero1<<<(int)(((size_t)N * 260 * 64 + 255) / 256), 256, 0, stream>>>(d2h, N, 66, 66, 64);
  deconv_bf16_xt<128, 64, 32, 32, 34, 34, 66, 66, 2, 1>
      <<<N * 8, 256, 0, stream>>>(d1h, ad1h, db1, d2h);
  ring_zero1<<<(int)((NH * 516 * 32 + 255) / 256), 256, 0, stream>>>(d3h, NH, 130, 130, 32);
  for (int half = 0; half < 2; ++half) {
    const int n0 = half * NH;
    deconv_bf16_xt<64, 32, 64, 64, 66, 66, 130, 130, 2, 0>
        <<<NH * 32, 256, 0, stream>>>(d2h + (size_t)n0 * 66 * 66 * 64,
                                      ad2h, db2, d3h);
    dec3_xt<<<NH * 16384 / 256, 256, 0, stream>>>(
        d3h, dw3, db3, outp + (size_t)n0 * 65536, NH);
  }
}

// Round 14
// 536.367 us; speedup vs baseline: 1.1662x; 1.0000x over previous
//
#include <hip/hip_runtime.h>

// ---------------------------------------------------------------------------
// VQ-VAE forward (NCHW). Round 23: retry of R22 (A staging via direct
//  global_load_lds, 16B) -- R22 bench died with "container failed twice"
//  (no compile/correctness error surfaced; likely infra, possibly the
//  address-space cast form). This retry keeps the R22 design byte-identical
//  except the casts use typed uint32_t address-space pointers (the
//  composable-kernel idiom). If this fails again, next round reverts to
//  R21-exact and the global_load_lds lever is abandoned.
//  Design recap (R21 -> R22): per super-tap each thread previously did
//  8 global_load_dwordx4 -> 32 VGPR -> 8 ds_write_b128; now A slices stream
//  directly global->LDS (no VGPR round-trip, no ds_writes), issued at TOP
//  of the super-tap into the inactive buffer (race-free: its readers all
//  passed the previous barrier); 96 MFMAs cover flight; end-of-super-tap
//  barrier (compiler vmcnt drain) gates readers. Lane LDS target =
//  wave_base + lane*16 (linear, documented constraint).
//  A bytes, B path, MFMA order bit-identical -> absmax 2.441e-4 exact.
// ---------------------------------------------------------------------------

using short8  = __attribute__((ext_vector_type(8))) short;
using short4v = __attribute__((ext_vector_type(4))) short;
using floatx4 = __attribute__((ext_vector_type(4))) float;

__device__ inline unsigned short bf16rn(float f) {
  unsigned u = __float_as_uint(f);
  unsigned r = (u + 0x7fffu + ((u >> 16) & 1u)) >> 16;
  return (unsigned short)r;
}
__device__ inline float bf2f1(short h) {
  return __uint_as_float(((unsigned)(unsigned short)h) << 16);
}

// ---- direct global->LDS 16B async copy (gfx950) --------------------------
typedef __attribute__((address_space(1))) const unsigned int guint_t;
typedef __attribute__((address_space(3))) unsigned int luint_t;
__device__ inline void gl_lds16(const short* g, short* l) {
  __builtin_amdgcn_global_load_lds((guint_t*)g, (luint_t*)l, 16, 0, 0);
}

// ---- deconv tap tables: entry e -> (ky,kx) weight tap
__device__ const int DKY[9]  = {1, 1, 1, 2, 0, 2, 2, 0, 0};
__device__ const int DKX[9]  = {1, 2, 0, 1, 1, 2, 0, 2, 0};

// ---------------- ring zero (split pair) ----------------------------------
__global__ __launch_bounds__(256) void ring_zero(short* __restrict__ h,
                                                 short* __restrict__ l,
                                                 int nimg, int PH, int PW, int C) {
  const int RC = (2 * PW + 2 * (PH - 2)) * C;
  int t = blockIdx.x * 256 + threadIdx.x;
  if (t >= nimg * RC) return;
  const int nl = t / RC;
  int rem = t - nl * RC;
  const int p = rem / C;
  const int ch = rem - p * C;
  int r, c;
  if (p < 2 * PW) {
    r = (p < PW) ? 0 : PH - 1;
    c = (p < PW) ? p : p - PW;
  } else {
    int q = p - 2 * PW;
    if (q < PH - 2) { r = 1 + q; c = 0; }
    else { r = 1 + q - (PH - 2); c = PW - 1; }
  }
  const size_t a = (((size_t)nl * PH + r) * PW + c) * C + ch;
  h[a] = 0; l[a] = 0;
}

// ---------------- ring zero (single buffer) -------------------------------
__global__ __launch_bounds__(256) void ring_zero1(short* __restrict__ h,
                                                  int nimg, int PH, int PW, int C) {
  const int RC = (2 * PW + 2 * (PH - 2)) * C;
  int t = blockIdx.x * 256 + threadIdx.x;
  if (t >= nimg * RC) return;
  const int nl = t / RC;
  int rem = t - nl * RC;
  const int p = rem / C;
  const int ch = rem - p * C;
  int r, c;
  if (p < 2 * PW) {
    r = (p < PW) ? 0 : PH - 1;
    c = (p < PW) ? p : p - PW;
  } else {
    int q = p - 2 * PW;
    if (q < PH - 2) { r = 1 + q; c = 0; }
    else { r = 1 + q - (PH - 2); c = PW - 1; }
  }
  h[(((size_t)nl * PH + r) * PW + c) * C + ch] = 0;
}

// ---------------- conv1: fp32 direct, writes xt [nh][130][130][32] --------
__global__ __launch_bounds__(256) void conv1_xt(const float* __restrict__ x,
                                                const float* __restrict__ w,
                                                const float* __restrict__ bias,
                                                short* __restrict__ oh,
                                                short* __restrict__ ol, int NH) {
  int t = blockIdx.x * 256 + threadIdx.x;
  if (t >= NH * 128 * 128) return;
  const int px = t & 16383;
  const int n  = t >> 14;
  const int r = px >> 7, c = px & 127;
  const int ih0 = 2 * r - 1, iw0 = 2 * c - 1;
  float acc[32];
#pragma unroll
  for (int o = 0; o < 32; ++o) acc[o] = bias[o];
  const float* ip = x + (size_t)n * 2 * 65536;
#pragma unroll
  for (int ic = 0; ic < 2; ++ic, ip += 65536) {
    float v[9];
#pragma unroll
    for (int kh = 0; kh < 3; ++kh) {
      const int ih = ih0 + kh;
#pragma unroll
      for (int kw = 0; kw < 3; ++kw) {
        const int iw = iw0 + kw;
        const bool ok = (ih >= 0) && (ih < 256) && (iw < 256) && (iw >= 0);
        v[kh * 3 + kw] = ok ? ip[ih * 256 + iw] : 0.f;
      }
    }
#pragma unroll
    for (int o = 0; o < 32; ++o) {
      float s = acc[o];
#pragma unroll
      for (int k = 0; k < 9; ++k) s = fmaf(v[k], w[(o * 2 + ic) * 9 + k], s);
      acc[o] = s;
    }
  }
  const size_t base = (((size_t)n * 130 + r + 1) * 130 + (c + 1)) * 32;
  short8 vh[4], vl[4];
#pragma unroll
  for (int g = 0; g < 4; ++g) {
#pragma unroll
    for (int kk = 0; kk < 8; ++kk) {
      const float rv = fmaxf(acc[g * 8 + kk], 0.f);
      const unsigned short hh = bf16rn(rv);
      vh[g][kk] = (short)hh;
      vl[g][kk] = (short)bf16rn(rv - __uint_as_float((unsigned)hh << 16));
    }
    *(short8*)(oh + base + g * 8) = vh[g];
    *(short8*)(ol + base + g * 8) = vl[g];
  }
}

// ---------------- fused weight/table prep (R15) ---------------------------
template<int CIN, int COUT>
__device__ inline void wprep_conv_body(int t, const float* __restrict__ w,
                                       short* __restrict__ hi,
                                       short* __restrict__ lo) {
  constexpr int MT = COUT / 16;
  const int j = t & 7;
  const int lane = (t >> 3) & 63;
  const int g = t >> 9;
  const int mt = g % MT;
  const int s = g / MT;
  const int icb = s / 9, tap = s - icb * 9;
  const int kh = tap / 3, kw = tap - kh * 3;
  const int m = mt * 16 + (lane & 15);
  const int ic = icb * 32 + ((lane >> 4) << 3) + j;
  const float v = w[((m * CIN + ic) * 3 + kh) * 3 + kw];
  const unsigned short h = bf16rn(v);
  hi[t] = (short)h;
  lo[t] = (short)bf16rn(v - __uint_as_float((unsigned)h << 16));
}

template<int CIN, int COUT>
__device__ inline void wprep_dec_body(int t, const float* __restrict__ w,
                                      short* __restrict__ hi) {
  constexpr int MT = COUT / 16, ICB = CIN / 32;
  const int j = t & 7;
  const int lane = (t >> 3) & 63;
  const int g = t >> 9;
  const int mt = g % MT;
  const int u = g / MT;
  const int icb = u % ICB;
  const int e = u / ICB;
  const int ky = DKY[e], kx = DKX[e];
  const int m = mt * 16 + (lane & 15);
  const int ic = icb * 32 + ((lane >> 4) << 3) + j;
  hi[t] = (short)bf16rn(w[((ic * COUT + m) * 3 + ky) * 3 + kx]);
}

__global__ __launch_bounds__(256) void prep_all(
    const float* __restrict__ w2, const float* __restrict__ w3,
    const float* __restrict__ w4, const float* __restrict__ dw1,
    const float* __restrict__ dw2, const float* __restrict__ emb,
    short* __restrict__ a2h, short* __restrict__ a2l,
    short* __restrict__ a3h, short* __restrict__ a3l,
    short* __restrict__ a4h, short* __restrict__ a4l,
    short* __restrict__ ad1h, short* __restrict__ ad2h,
    float* __restrict__ nrm, short* __restrict__ ebh,
    short* __restrict__ ebl) {
  const int bb = blockIdx.x;
  const int tid = threadIdx.x;
  if (bb < 72) {
    wprep_conv_body<32, 64>(bb * 256 + tid, w2, a2h, a2l);
  } else if (bb < 360) {
    wprep_conv_body<64, 128>((bb - 72) * 256 + tid, w3, a3h, a3l);
  } else if (bb < 936) {
    wprep_conv_body<128, 128>((bb - 360) * 256 + tid, w4, a4h, a4l);
  } else if (bb < 1224) {
    wprep_dec_body<128, 64>((bb - 936) * 256 + tid, dw1, ad1h);
  } else if (bb < 1296) {
    wprep_dec_body<64, 32>((bb - 1224) * 256 + tid, dw2, ad2h);
  } else if (bb < 1424) {
    const int t = (bb - 1296) * 256 + tid;   // < 32768
    const int j  = t & 7;
    const int l  = (t >> 3) & 63;
    const int kk = (t >> 9) & 1;
    const int ct = t >> 10;
    const int code = ct * 16 + (l & 15);
    const int k = kk * 32 + ((l >> 4) << 3) + j;
    const float v = emb[code * 64 + k];
    const unsigned short h = bf16rn(v);
    ebh[t] = (short)h;
    ebl[t] = (short)bf16rn(v - __uint_as_float((unsigned)h << 16));
  } else {
    const int jj = (bb - 1424) * 256 + tid;
    if (jj < 512) {
      float s = 0.f;
      const float* e = emb + jj * 64;
#pragma unroll
      for (int k = 0; k < 64; ++k) s = fmaf(e[k], e[k], s);
      nrm[jj] = s;
    }
  }
}

// ------- generic strided conv MFMA (split xt -> split xt), NP tiles -------
// R23: A staged 2 tap-slices per buffer via direct global_load_lds (16B),
// issued at top of super-tap; one barrier per 2 taps.
template<int CIN, int COUT, int OH, int OW, int S, int PHI, int PWI, int PHO, int PWO, int NP>
__global__ __launch_bounds__(256) void conv_mfma_xt(
    const short* __restrict__ xih, const short* __restrict__ xil,
    const short* __restrict__ ah,  const short* __restrict__ al,
    const float* __restrict__ bias,
    short* __restrict__ xoh, short* __restrict__ xol) {
  constexpr int MT = COUT / 16, ICB = CIN / 32;
  constexpr int PXB = 64 * NP, TPB = OH * OW / PXB;
  constexpr int NSL = ICB * 9;            // total A slices
  constexpr int NST = (NSL + 1) / 2;      // super-taps (2 slices each)
  constexpr int CH  = MT * 64;            // short8 chunks per slice
  constexpr int C2  = 2 * CH;             // chunks per buffer
  constexpr int CPT = (C2 + 255) / 256;   // chunks per thread
  __shared__ short ash[2][C2 * 8];
  __shared__ short asl2[2][C2 * 8];
  const int b = blockIdx.x;
  const int n = b / TPB, pt = b % TPB;
  const int tid = threadIdx.x;
  const int lane = tid & 63, wave = tid >> 6;
  const int quad = lane >> 4;
  int rr[NP], cc[NP];
  size_t bbase[NP];
#pragma unroll
  for (int p = 0; p < NP; ++p) {
    const int pl = pt * PXB + wave * (16 * NP) + p * 16 + (lane & 15);
    rr[p] = pl / OW; cc[p] = pl % OW;
    bbase[p] = (((size_t)n * PHI + S * rr[p]) * PWI + S * cc[p]) * CIN + quad * 8;
  }

  floatx4 acc[MT][NP];
#pragma unroll
  for (int mt = 0; mt < MT; ++mt)
#pragma unroll
    for (int p = 0; p < NP; ++p) acc[mt][p] = (floatx4){0.f, 0.f, 0.f, 0.f};

  // prologue: async-stage slices 0..1 into buffer 0
#pragma unroll
  for (int c = 0; c < CPT; ++c) {
    const int idx = tid + c * 256;
    if (idx < C2 && idx < NSL * CH) {
      gl_lds16(ah + (size_t)idx * 8, ash[0] + idx * 8);
      gl_lds16(al + (size_t)idx * 8, asl2[0] + idx * 8);
    }
  }
  __syncthreads();

  for (int st = 0; st < NST; ++st) {
    // issue next super-tap's slices directly into the inactive buffer
    if (st + 1 < NST) {
      const int base = (st + 1) * C2;
      const int nb = (st + 1) & 1;
#pragma unroll
      for (int c = 0; c < CPT; ++c) {
        const int idx = tid + c * 256;
        if (idx < C2 && base + idx < NSL * CH) {
          gl_lds16(ah + (size_t)(base + idx) * 8, ash[nb] + idx * 8);
          gl_lds16(al + (size_t)(base + idx) * 8, asl2[nb] + idx * 8);
        }
      }
    }
#pragma unroll
    for (int t2 = 0; t2 < 2; ++t2) {
      const int s = st * 2 + t2;
      if (s < NSL) {
        const int icb = s / 9, tap = s - icb * 9;
        const int kh = tap / 3, kw = tap - kh * 3;
        short8 bh[NP], bl[NP];
#pragma unroll
        for (int p = 0; p < NP; ++p) {
          const size_t be = bbase[p] + (size_t)(kh * PWI + kw) * CIN + icb * 32;
          bh[p] = *(const short8*)(xih + be);
          bl[p] = *(const short8*)(xil + be);
        }
        const short8* __restrict__ a8h = (const short8*)ash[st & 1] + t2 * CH;
        const short8* __restrict__ a8l = (const short8*)asl2[st & 1] + t2 * CH;
#pragma unroll
        for (int mt = 0; mt < MT; ++mt) {
          const short8 wh = a8h[mt * 64 + lane];
          const short8 wl = a8l[mt * 64 + lane];
#pragma unroll
          for (int p = 0; p < NP; ++p) {
            acc[mt][p] = __builtin_amdgcn_mfma_f32_16x16x32_bf16(wh, bh[p], acc[mt][p], 0, 0, 0);
            acc[mt][p] = __builtin_amdgcn_mfma_f32_16x16x32_bf16(wh, bl[p], acc[mt][p], 0, 0, 0);
            acc[mt][p] = __builtin_amdgcn_mfma_f32_16x16x32_bf16(wl, bh[p], acc[mt][p], 0, 0, 0);
          }
        }
      }
    }
    if (st + 1 < NST) __syncthreads();
  }
#pragma unroll
  for (int p = 0; p < NP; ++p) {
    const size_t ob = (((size_t)n * PHO + rr[p] + 1) * PWO + (cc[p] + 1)) * COUT + quad * 4;
#pragma unroll
    for (int mt = 0; mt < MT; ++mt) {
      short4v sh, sl;
#pragma unroll
      for (int q = 0; q < 4; ++q) {
        const float v = fmaxf(acc[mt][p][q] + bias[mt * 16 + quad * 4 + q], 0.f);
        const unsigned short hh = bf16rn(v);
        sh[q] = (short)hh;
        sl[q] = (short)bf16rn(v - __uint_as_float((unsigned)hh << 16));
      }
      *(short4v*)(xoh + ob + mt * 16) = sh;
      *(short4v*)(xol + ob + mt * 16) = sl;
    }
  }
}

// ---- fused transposed conv, plain bf16, NP pixel-tiles per wave ----------
// R15: ASTG=1 stages the per-icb A group (9 e-slices) in LDS, double-buffered.
template<int CIN, int COUT, int IH, int IW, int PHI, int PWI, int PHO, int PWO, int NP, int ASTG>
__global__ __launch_bounds__(256) void deconv_bf16_xt(
    const short* __restrict__ xih, const short* __restrict__ ah,
    const float* __restrict__ bias, short* __restrict__ xoh) {
  constexpr int MT = COUT / 16, ICB = CIN / 32;
  constexpr int PXB = 64 * NP, TPB = IH * IW / PXB;
  constexpr int CHI = 9 * MT * 64;               // chunks per icb A-group
  constexpr int CPT = (CHI + 255) / 256;
  constexpr int PHE[9] = {0, 1, 1, 2, 2, 3, 3, 3, 3};
  constexpr int DE[9]  = {0, 0, 1, 0, 2, 0, 1, 2, 3};
  __shared__ short ash[ASTG ? 2 * CHI * 8 : 1];
  const int b = blockIdx.x;
  const int n = b / TPB, pt = b % TPB;
  const int tid = threadIdx.x;
  const int lane = tid & 63, wave = tid >> 6;
  const int quad = lane >> 4;
  int ii[NP], jj[NP];
  size_t p00[NP];
#pragma unroll
  for (int p = 0; p < NP; ++p) {
    const int pl = pt * PXB + wave * (16 * NP) + p * 16 + (lane & 15);
    ii[p] = pl / IW; jj[p] = pl % IW;
    p00[p] = (((size_t)n * PHI + (ii[p] + 1)) * PWI + (jj[p] + 1)) * CIN + quad * 8;
  }

  floatx4 acc[4][MT][NP];
#pragma unroll
  for (int ph = 0; ph < 4; ++ph)
#pragma unroll
    for (int mt = 0; mt < MT; ++mt)
#pragma unroll
      for (int p = 0; p < NP; ++p) acc[ph][mt][p] = (floatx4){0.f, 0.f, 0.f, 0.f};

  const short8* __restrict__ ah8 = (const short8*)ah;

  short8 ra[ASTG ? CPT : 1];
  if constexpr (ASTG) {
    // prologue: stage icb0's 9 e-slices into buffer 0
#pragma unroll
    for (int c = 0; c < CPT; ++c) {
      const int idx = tid + c * 256;
      if (idx < CHI) {
        const int e = idx / (MT * 64);
        const int rem = idx - e * (MT * 64);
        ra[c] = ah8[(e * ICB + 0) * (MT * 64) + rem];
      }
    }
#pragma unroll
    for (int c = 0; c < CPT; ++c) {
      const int idx = tid + c * 256;
      if (idx < CHI) *(short8*)(ash + idx * 8) = ra[c];
    }
    __syncthreads();
  }

  for (int icb = 0; icb < ICB; ++icb) {
    short8 bh[NP][4];
#pragma unroll
    for (int p = 0; p < NP; ++p)
#pragma unroll
      for (int d = 0; d < 4; ++d)
        bh[p][d] = *(const short8*)(xih + p00[p] +
                                    (size_t)((d >> 1) * PWI + (d & 1)) * CIN + icb * 32);
    if constexpr (ASTG) {
      if (icb + 1 < ICB) {
#pragma unroll
        for (int c = 0; c < CPT; ++c) {
          const int idx = tid + c * 256;
          if (idx < CHI) {
            const int e = idx / (MT * 64);
            const int rem = idx - e * (MT * 64);
            ra[c] = ah8[(e * ICB + icb + 1) * (MT * 64) + rem];
          }
        }
      }
    }
#pragma unroll
    for (int e = 0; e < 9; ++e) {
      const int ph = PHE[e], d = DE[e];
#pragma unroll
      for (int mt = 0; mt < MT; ++mt) {
        short8 wh;
        if constexpr (ASTG)
          wh = ((const short8*)(ash + (size_t)(icb & 1) * CHI * 8))[(e * MT + mt) * 64 + lane];
        else
          wh = ah8[((e * ICB + icb) * MT + mt) * 64 + lane];
#pragma unroll
        for (int p = 0; p < NP; ++p)
          acc[ph][mt][p] = __builtin_amdgcn_mfma_f32_16x16x32_bf16(
              wh, bh[p][d], acc[ph][mt][p], 0, 0, 0);
      }
    }
    if constexpr (ASTG) {
      if (icb + 1 < ICB) {
        const size_t nb = (size_t)((icb + 1) & 1) * CHI * 8;
#pragma unroll
        for (int c = 0; c < CPT; ++c) {
          const int idx = tid + c * 256;
          if (idx < CHI) *(short8*)(ash + nb + idx * 8) = ra[c];
        }
        __syncthreads();
      }
    }
  }
#pragma unroll
  for (int p = 0; p < NP; ++p)
#pragma unroll
    for (int ph = 0; ph < 4; ++ph) {
      const int oy = 2 * ii[p] + (ph >> 1), ox = 2 * jj[p] + (ph & 1);
      const size_t ob = (((size_t)n * PHO + oy + 1) * PWO + (ox + 1)) * COUT + quad * 4;
#pragma unroll
      for (int mt = 0; mt < MT; ++mt) {
        short4v sh;
#pragma unroll
        for (int q = 0; q < 4; ++q)
          sh[q] = (short)bf16rn(fmaxf(acc[ph][mt][p][q] + bias[mt * 16 + quad * 4 + q], 0.f));
        *(short4v*)(xoh + ob + mt * 16) = sh;
      }
    }
}

// ---------------- conv4 MFMA (R23): 2-tap A staging via global_load_lds ---
// 256 thr, 4 waves, grid N*8, NP=2; B just-in-time from global; A slices
// streamed directly into LDS (no VGPR round-trip), 18 barriers.
__global__ __launch_bounds__(256) void conv4_mfma(
    const short* __restrict__ xthi, const short* __restrict__ xtlo,
    const short* __restrict__ ahi,  const short* __restrict__ alo,
    const float* __restrict__ bias,
    short* __restrict__ ench, short* __restrict__ encl) {
  __shared__ short ash[2][8192];        // 2 x 16384 B (A hi, two tap slices)
  __shared__ short asl[2][8192];        // 2 x 16384 B (A lo)
  const int b    = blockIdx.x;          // N*8 blocks, 128 pixels each
  const int n    = b >> 3;
  const int pt   = b & 7;
  const int tid  = threadIdx.x;
  const int lane = tid & 63;
  const int wave = tid >> 6;
  const int kq   = lane >> 4;
  int pl[2];
  size_t bbase[2];
#pragma unroll
  for (int p = 0; p < 2; ++p) {
    pl[p] = pt * 128 + wave * 32 + p * 16 + (lane & 15);
    const int r = pl[p] >> 5, c = pl[p] & 31;
    bbase[p] = (((size_t)n * 34 + r) * 34 + c) * 128 + kq * 8;
  }

  floatx4 acc[8][2];
#pragma unroll
  for (int mt = 0; mt < 8; ++mt)
#pragma unroll
    for (int p = 0; p < 2; ++p) acc[mt][p] = (floatx4){0.f, 0.f, 0.f, 0.f};

  // prologue: async-stage tap-slices 0,1 into buffer 0
#pragma unroll
  for (int c = 0; c < 4; ++c) {
    const int idx = tid + c * 256;
    gl_lds16(ahi + (size_t)idx * 8, ash[0] + idx * 8);
    gl_lds16(alo + (size_t)idx * 8, asl[0] + idx * 8);
  }
  __syncthreads();

  for (int st = 0; st < 18; ++st) {
    // issue next super-tap's 2 A slices directly into the inactive buffer
    if (st < 17) {
      const int base = (st + 1) * 1024;
      const int nbuf = (st + 1) & 1;
#pragma unroll
      for (int c = 0; c < 4; ++c) {
        const int idx = tid + c * 256;
        gl_lds16(ahi + (size_t)(base + idx) * 8, ash[nbuf] + idx * 8);
        gl_lds16(alo + (size_t)(base + idx) * 8, asl[nbuf] + idx * 8);
      }
    }
#pragma unroll
    for (int t2 = 0; t2 < 2; ++t2) {
      const int s = st * 2 + t2;
      const int icb = s / 9, tap = s - icb * 9;
      const int kh = tap / 3, kw = tap - kh * 3;
      const short8* __restrict__ a8h = (const short8*)ash[st & 1] + t2 * 512;
      const short8* __restrict__ a8l = (const short8*)asl[st & 1] + t2 * 512;
      short8 bh[2], bl[2];
#pragma unroll
      for (int p = 0; p < 2; ++p) {
        const size_t be = bbase[p] + (size_t)(kh * 34 + kw) * 128 + icb * 32;
        bh[p] = *(const short8*)(xthi + be);
        bl[p] = *(const short8*)(xtlo + be);
      }
#pragma unroll
      for (int mt = 0; mt < 8; ++mt) {
        const short8 ah = a8h[mt * 64 + lane];
        const short8 al = a8l[mt * 64 + lane];
#pragma unroll
        for (int p = 0; p < 2; ++p) {
          acc[mt][p] = __builtin_amdgcn_mfma_f32_16x16x32_bf16(ah, bh[p], acc[mt][p], 0, 0, 0);
          acc[mt][p] = __builtin_amdgcn_mfma_f32_16x16x32_bf16(ah, bl[p], acc[mt][p], 0, 0, 0);
          acc[mt][p] = __builtin_amdgcn_mfma_f32_16x16x32_bf16(al, bh[p], acc[mt][p], 0, 0, 0);
        }
      }
    }
    if (st < 17) __syncthreads();
  }
#pragma unroll
  for (int p = 0; p < 2; ++p) {
    const size_t obase = (size_t)n * 128 * 1024 + pl[p];
#pragma unroll
    for (int mt = 0; mt < 8; ++mt) {
#pragma unroll
      for (int q = 0; q < 4; ++q) {
        const int cout = mt * 16 + kq * 4 + q;
        const float rr = fmaxf(acc[mt][p][q] + bias[cout], 0.f);
        const unsigned short h = bf16rn(rr);
        const size_t oi = obase + (size_t)cout * 1024;
        ench[oi] = (short)h;
        encl[oi] = (short)bf16rn(rr - __uint_as_float((unsigned)h << 16));
      }
    }
  }
}

// ---- vq_mfma (R14): block = (n, one 64-px block, all 128 ch) -------------
__global__ __launch_bounds__(256) void vq_mfma(
    const short* __restrict__ fhi, const short* __restrict__ flo,
    const short* __restrict__ ebh, const short* __restrict__ ebl,
    const float* __restrict__ nrm, const float* __restrict__ emb,
    short* __restrict__ d1h) {
  __shared__ int sidx[128];
  const int lane = threadIdx.x & 63;
  const int wave = threadIdx.x >> 6;
  const int n  = blockIdx.x >> 4;
  const int pb = blockIdx.x & 15;

  short8 ah0[2], ah1[2], al0[2], al1[2];
#pragma unroll
  for (int g = 0; g < 2; ++g) {
    const int ch = wave * 32 + g * 16 + (lane & 15);
    const size_t abase = (((size_t)(n * 128 + ch)) * 16 + pb) * 64 + ((lane >> 4) << 3);
    ah0[g] = *(const short8*)(fhi + abase);
    ah1[g] = *(const short8*)(fhi + abase + 32);
    al0[g] = *(const short8*)(flo + abase);
    al1[g] = *(const short8*)(flo + abase + 32);
  }

  float bestv[2][4];
  int   besti[2][4];
#pragma unroll
  for (int g = 0; g < 2; ++g)
#pragma unroll
    for (int q = 0; q < 4; ++q) { bestv[g][q] = 3.4e38f; besti[g][q] = 0; }

  const short8* __restrict__ ebh8 = (const short8*)ebh;
  const short8* __restrict__ ebl8 = (const short8*)ebl;
  for (int ct = 0; ct < 32; ++ct) {
    const int f0 = (ct * 2) * 64 + lane;
    const short8 b0h = ebh8[f0];
    const short8 b1h = ebh8[f0 + 64];
    const short8 b0l = ebl8[f0];
    const short8 b1l = ebl8[f0 + 64];
    const int code = ct * 16 + (lane & 15);
    const float nn = nrm[code];
#pragma unroll
    for (int g = 0; g < 2; ++g) {
      floatx4 acc = {0.f, 0.f, 0.f, 0.f};
      acc = __builtin_amdgcn_mfma_f32_16x16x32_bf16(ah0[g], b0h, acc, 0, 0, 0);
      acc = __builtin_amdgcn_mfma_f32_16x16x32_bf16(ah1[g], b1h, acc, 0, 0, 0);
      acc = __builtin_amdgcn_mfma_f32_16x16x32_bf16(ah0[g], b0l, acc, 0, 0, 0);
      acc = __builtin_amdgcn_mfma_f32_16x16x32_bf16(ah1[g], b1l, acc, 0, 0, 0);
      acc = __builtin_amdgcn_mfma_f32_16x16x32_bf16(al0[g], b0h, acc, 0, 0, 0);
      acc = __builtin_amdgcn_mfma_f32_16x16x32_bf16(al1[g], b1h, acc, 0, 0, 0);
#pragma unroll
      for (int q = 0; q < 4; ++q) {
        const float sc = nn - 2.f * acc[q];
        if (sc < bestv[g][q]) { bestv[g][q] = sc; besti[g][q] = code; }
      }
    }
  }
#pragma unroll
  for (int off = 1; off < 16; off <<= 1) {
#pragma unroll
    for (int g = 0; g < 2; ++g)
#pragma unroll
      for (int q = 0; q < 4; ++q) {
        const float ov = __shfl_xor(bestv[g][q], off, 64);
        const int   oi = __shfl_xor(besti[g][q], off, 64);
        if (ov < bestv[g][q] || (ov == bestv[g][q] && oi < besti[g][q])) {
          bestv[g][q] = ov; besti[g][q] = oi;
        }
      }
  }
  if ((lane & 15) == 0) {
#pragma unroll
    for (int g = 0; g < 2; ++g)
#pragma unroll
      for (int q = 0; q < 4; ++q)
        sidx[wave * 32 + g * 16 + (lane >> 4) * 4 + q] = besti[g][q];
  }
  __syncthreads();
  const int chg = (threadIdx.x & 15) * 8;
  int gi8[8];
#pragma unroll
  for (int k = 0; k < 8; ++k) gi8[k] = sidx[chg + k];
#pragma unroll
  for (int pxg = 0; pxg < 4; ++pxg) {
    const int p = pxg * 16 + (threadIdx.x >> 4);   // 0..63
    const int pix = pb * 64 + p;
    const int r = pix >> 5, c = pix & 31;
    short8 v;
#pragma unroll
    for (int k = 0; k < 8; ++k)
      v[k] = (short)bf16rn(emb[(size_t)gi8[k] * 64 + p]);
    *(short8*)(d1h + (((size_t)n * 34 + r + 1) * 34 + (c + 1)) * 128 + chg) = v;
  }
}

// ---------------- dec3: fp32 direct from single-bf16 xt input -------------
__global__ __launch_bounds__(256) void dec3_xt(const short* __restrict__ xh,
                                               const float* __restrict__ w,
                                               const float* __restrict__ bias,
                                               float* __restrict__ out, int NH) {
  int t = blockIdx.x * 256 + threadIdx.x;
  if (t >= NH * 128 * 128) return;
  const int px = t & 16383;
  const int nl = t >> 14;
  const int i = px >> 7, j = px & 127;
  const float b0 = bias[0];
  float a00 = b0, a01 = b0, a10 = b0, a11 = b0;
  const size_t base00 = (((size_t)nl * 130 + i + 1) * 130 + (j + 1)) * 32;
#pragma unroll
  for (int icg = 0; icg < 4; ++icg) {
    const short8 h00 = *(const short8*)(xh + base00 + icg * 8);
    const short8 h01 = *(const short8*)(xh + base00 + 32 + icg * 8);
    const short8 h10 = *(const short8*)(xh + base00 + 130 * 32 + icg * 8);
    const short8 h11 = *(const short8*)(xh + base00 + 130 * 32 + 32 + icg * 8);
#pragma unroll
    for (int kk = 0; kk < 8; ++kk) {
      const int ic = icg * 8 + kk;
      const float x00 = bf2f1(h00[kk]);
      const float x01 = bf2f1(h01[kk]);
      const float x10 = bf2f1(h10[kk]);
      const float x11 = bf2f1(h11[kk]);
      const float* wp = w + ic * 9;
      a00 = fmaf(x00, wp[4], a00);
      a01 = fmaf(x00, wp[5], fmaf(x01, wp[3], a01));
      a10 = fmaf(x00, wp[7], fmaf(x10, wp[1], a10));
      a11 = fmaf(x00, wp[8], fmaf(x01, wp[6], fmaf(x10, wp[2], fmaf(x11, wp[0], a11))));
    }
  }
  float* op = out + ((size_t)nl * 256 + 2 * i) * 256 + 2 * j;
  op[0] = a00; op[1] = a01; op[256] = a10; op[257] = a11;
}

// ---------------------------------------------------------------------------
extern "C" void kernel_launch(void* const* d_in, const int* in_sizes, int n_in,
                              void* d_out, int out_size, void* d_ws, size_t ws_size,
                              hipStream_t stream) {
  const float* x   = (const float*)d_in[0];
  const float* w1  = (const float*)d_in[1];
  const float* b1  = (const float*)d_in[2];
  const float* w2  = (const float*)d_in[3];
  const float* b2  = (const float*)d_in[4];
  const float* w3  = (const float*)d_in[5];
  const float* b3  = (const float*)d_in[6];
  const float* w4  = (const float*)d_in[7];
  const float* b4  = (const float*)d_in[8];
  const float* emb = (const float*)d_in[9];
  const float* dw1 = (const float*)d_in[10];
  const float* db1 = (const float*)d_in[11];
  const float* dw2 = (const float*)d_in[12];
  const float* db2 = (const float*)d_in[13];
  const float* dw3 = (const float*)d_in[14];
  const float* db3 = (const float*)d_in[15];
  float* outp = (float*)d_out;

  const int N = in_sizes[0] / (2 * 256 * 256);  // 64
  if (N & 1) return;
  const int NH = N / 2;

  // ---- arena (units: floats; 1 float = 2 shorts); R7-proven footprint ----
  const size_t sx3 = (size_t)N * 66 * 66 * 64;
  const size_t sx2 = (size_t)NH * 130 * 130 * 32;
  const size_t sx4 = (size_t)N * 34 * 34 * 128;
  const size_t se  = (size_t)N * 128 * 1024;
  const size_t sd1 = sx4;
  const size_t smalls = 512 + 18432 + 73728 + 147456 + 73728 + 18432 + 32768;
  const size_t need = (sx3 + sx4 + se + sd1 + smalls) * sizeof(float);
  if (ws_size < need) return;

  float* ws = (float*)d_ws;
  short* x3h = (short*)ws;                 short* x3l = x3h + sx3;   // enc split
  short* x2h = (short*)(ws + sx3);         short* x2l = x2h + sx2;
  short* x4h = (short*)(ws + sx3);         short* x4l = x4h + sx4;
  short* ech = (short*)(ws + sx3 + sx4);   short* ecl = ech + se;
  short* d1h = (short*)(ws + sx3 + sx4 + se);   // bf16-only decoder bufs
  short* d2h = (short*)ws;
  short* d3h = (short*)(ws + sx3);
  float* sm  = ws + sx3 + sx4 + se + sd1;
  float* nrm = sm;
  short* a2h = (short*)(sm + 512);                         short* a2l = a2h + 18432;
  short* a3h = (short*)(sm + 512 + 18432);                 short* a3l = a3h + 73728;
  short* a4h = (short*)(sm + 512 + 18432 + 73728);         short* a4l = a4h + 147456;
  short* ad1h = (short*)(sm + 512 + 18432 + 73728 + 147456);           // hi only
  short* ad2h = (short*)(sm + 512 + 18432 + 73728 + 147456 + 73728);   // hi only
  short* ebh = (short*)(sm + 512 + 18432 + 73728 + 147456 + 73728 + 18432); short* ebl = ebh + 32768;

  // ---- fused weight preps + VQ tables (R15) ----
  prep_all<<<1426, 256, 0, stream>>>(w2, w3, w4, dw1, dw2, emb,
                                     a2h, a2l, a3h, a3l, a4h, a4l,
                                     ad1h, ad2h, nrm, ebh, ebl);

  // ---- encoder (split-bf16, NP=2; A-LDS 2-tap async staged) ----
  ring_zero<<<(int)((NH * 516 * 32 + 255) / 256), 256, 0, stream>>>(x2h, x2l, NH, 130, 130, 32);
  ring_zero<<<(int)(((size_t)N * 260 * 64 + 255) / 256), 256, 0, stream>>>(x3h, x3l, N, 66, 66, 64);
  for (int half = 0; half < 2; ++half) {
    const int n0 = half * NH;
    conv1_xt<<<NH * 16384 / 256, 256, 0, stream>>>(
        x + (size_t)n0 * 2 * 65536, w1, b1, x2h, x2l, NH);
    conv_mfma_xt<32, 64, 64, 64, 2, 130, 130, 66, 66, 2>
        <<<NH * 32, 256, 0, stream>>>(x2h, x2l, a2h, a2l, b2,
                                      x3h + (size_t)n0 * 66 * 66 * 64,
                                      x3l + (size_t)n0 * 66 * 66 * 64);
  }
  ring_zero<<<(int)(((size_t)N * 132 * 128 + 255) / 256), 256, 0, stream>>>(x4h, x4l, N, 34, 34, 128);
  conv_mfma_xt<64, 128, 32, 32, 2, 66, 66, 34, 34, 2>
      <<<N * 8, 256, 0, stream>>>(x3h, x3l, a3h, a3l, b3, x4h, x4l);
  conv4_mfma<<<N * 8, 256, 0, stream>>>(x4h, x4l, a4h, a4l, b4, ech, ecl);

  // ---- VQ (split scoring, bf16 gather; R14 coalesced) ----
  ring_zero1<<<(int)(((size_t)N * 132 * 128 + 255) / 256), 256, 0, stream>>>(d1h, N, 34, 34, 128);
  vq_mfma<<<N * 16, 256, 0, stream>>>(ech, ecl, ebh, ebl, nrm, emb, d1h);

  // ---- decoder (plain bf16, NP=2; deconv1 A-LDS staged) ----
  ring_zero1<<<(int)(((size_t)N * 260 * 64 + 255) / 256), 256, 0, stream>>>(d2h, N, 66, 66, 64);
  deconv_bf16_xt<128, 64, 32, 32, 34, 34, 66, 66, 2, 1>
      <<<N * 8, 256, 0, stream>>>(d1h, ad1h, db1, d2h);
  ring_zero1<<<(int)((NH * 516 * 32 + 255) / 256), 256, 0, stream>>>(d3h, NH, 130, 130, 32);
  for (int half = 0; half < 2; ++half) {
    const int n0 = half * NH;
    deconv_bf16_xt<64, 32, 64, 64, 66, 66, 130, 130, 2, 0>
        <<<NH * 32, 256, 0, stream>>>(d2h + (size_t)n0 * 66 * 66 * 64,
                                      ad2h, db2, d3h);
    dec3_xt<<<NH * 16384 / 256, 256, 0, stream>>>(
        d3h, dw3, db3, outp + (size_t)n0 * 65536, NH);
  }
}

// Round 15
// 535.848 us; speedup vs baseline: 1.1674x; 1.0010x over previous
//
#include <hip/hip_runtime.h>

// ---------------------------------------------------------------------------
// VQ-VAE forward (NCHW). Round 24: per-kernel best-of recombination.
//  R23 post-mortem: total 536 (= R21) but composition moved: conv4 regressed
//  69.4->74.1 with global_load_lds (gl_lds stream shares VMEM queue with
//  just-in-time B loads; per-super-tap vmcnt(0) drain gates on both), while
//  conv_mfma_xt (conv3 + conv2 x2) GAINED ~4.7us (gl_lds removes an
//  issue/VALU-bound staging path there: 16 issues vs 32 insts + addr VALU).
//  This round: conv_mfma_xt keeps R23's gl_lds staging; conv4_mfma reverts
//  to the R20/R21 register-staged 2-tap version (proven 69.4us).
//  Numerics bit-identical -> absmax 2.441e-4 exact.
// ---------------------------------------------------------------------------

using short8  = __attribute__((ext_vector_type(8))) short;
using short4v = __attribute__((ext_vector_type(4))) short;
using floatx4 = __attribute__((ext_vector_type(4))) float;

__device__ inline unsigned short bf16rn(float f) {
  unsigned u = __float_as_uint(f);
  unsigned r = (u + 0x7fffu + ((u >> 16) & 1u)) >> 16;
  return (unsigned short)r;
}
__device__ inline float bf2f1(short h) {
  return __uint_as_float(((unsigned)(unsigned short)h) << 16);
}

// ---- direct global->LDS 16B async copy (gfx950) --------------------------
typedef __attribute__((address_space(1))) const unsigned int guint_t;
typedef __attribute__((address_space(3))) unsigned int luint_t;
__device__ inline void gl_lds16(const short* g, short* l) {
  __builtin_amdgcn_global_load_lds((guint_t*)g, (luint_t*)l, 16, 0, 0);
}

// ---- deconv tap tables: entry e -> (ky,kx) weight tap
__device__ const int DKY[9]  = {1, 1, 1, 2, 0, 2, 2, 0, 0};
__device__ const int DKX[9]  = {1, 2, 0, 1, 1, 2, 0, 2, 0};

// ---------------- ring zero (split pair) ----------------------------------
__global__ __launch_bounds__(256) void ring_zero(short* __restrict__ h,
                                                 short* __restrict__ l,
                                                 int nimg, int PH, int PW, int C) {
  const int RC = (2 * PW + 2 * (PH - 2)) * C;
  int t = blockIdx.x * 256 + threadIdx.x;
  if (t >= nimg * RC) return;
  const int nl = t / RC;
  int rem = t - nl * RC;
  const int p = rem / C;
  const int ch = rem - p * C;
  int r, c;
  if (p < 2 * PW) {
    r = (p < PW) ? 0 : PH - 1;
    c = (p < PW) ? p : p - PW;
  } else {
    int q = p - 2 * PW;
    if (q < PH - 2) { r = 1 + q; c = 0; }
    else { r = 1 + q - (PH - 2); c = PW - 1; }
  }
  const size_t a = (((size_t)nl * PH + r) * PW + c) * C + ch;
  h[a] = 0; l[a] = 0;
}

// ---------------- ring zero (single buffer) -------------------------------
__global__ __launch_bounds__(256) void ring_zero1(short* __restrict__ h,
                                                  int nimg, int PH, int PW, int C) {
  const int RC = (2 * PW + 2 * (PH - 2)) * C;
  int t = blockIdx.x * 256 + threadIdx.x;
  if (t >= nimg * RC) return;
  const int nl = t / RC;
  int rem = t - nl * RC;
  const int p = rem / C;
  const int ch = rem - p * C;
  int r, c;
  if (p < 2 * PW) {
    r = (p < PW) ? 0 : PH - 1;
    c = (p < PW) ? p : p - PW;
  } else {
    int q = p - 2 * PW;
    if (q < PH - 2) { r = 1 + q; c = 0; }
    else { r = 1 + q - (PH - 2); c = PW - 1; }
  }
  h[(((size_t)nl * PH + r) * PW + c) * C + ch] = 0;
}

// ---------------- conv1: fp32 direct, writes xt [nh][130][130][32] --------
__global__ __launch_bounds__(256) void conv1_xt(const float* __restrict__ x,
                                                const float* __restrict__ w,
                                                const float* __restrict__ bias,
                                                short* __restrict__ oh,
                                                short* __restrict__ ol, int NH) {
  int t = blockIdx.x * 256 + threadIdx.x;
  if (t >= NH * 128 * 128) return;
  const int px = t & 16383;
  const int n  = t >> 14;
  const int r = px >> 7, c = px & 127;
  const int ih0 = 2 * r - 1, iw0 = 2 * c - 1;
  float acc[32];
#pragma unroll
  for (int o = 0; o < 32; ++o) acc[o] = bias[o];
  const float* ip = x + (size_t)n * 2 * 65536;
#pragma unroll
  for (int ic = 0; ic < 2; ++ic, ip += 65536) {
    float v[9];
#pragma unroll
    for (int kh = 0; kh < 3; ++kh) {
      const int ih = ih0 + kh;
#pragma unroll
      for (int kw = 0; kw < 3; ++kw) {
        const int iw = iw0 + kw;
        const bool ok = (ih >= 0) && (ih < 256) && (iw < 256) && (iw >= 0);
        v[kh * 3 + kw] = ok ? ip[ih * 256 + iw] : 0.f;
      }
    }
#pragma unroll
    for (int o = 0; o < 32; ++o) {
      float s = acc[o];
#pragma unroll
      for (int k = 0; k < 9; ++k) s = fmaf(v[k], w[(o * 2 + ic) * 9 + k], s);
      acc[o] = s;
    }
  }
  const size_t base = (((size_t)n * 130 + r + 1) * 130 + (c + 1)) * 32;
  short8 vh[4], vl[4];
#pragma unroll
  for (int g = 0; g < 4; ++g) {
#pragma unroll
    for (int kk = 0; kk < 8; ++kk) {
      const float rv = fmaxf(acc[g * 8 + kk], 0.f);
      const unsigned short hh = bf16rn(rv);
      vh[g][kk] = (short)hh;
      vl[g][kk] = (short)bf16rn(rv - __uint_as_float((unsigned)hh << 16));
    }
    *(short8*)(oh + base + g * 8) = vh[g];
    *(short8*)(ol + base + g * 8) = vl[g];
  }
}

// ---------------- fused weight/table prep (R15) ---------------------------
template<int CIN, int COUT>
__device__ inline void wprep_conv_body(int t, const float* __restrict__ w,
                                       short* __restrict__ hi,
                                       short* __restrict__ lo) {
  constexpr int MT = COUT / 16;
  const int j = t & 7;
  const int lane = (t >> 3) & 63;
  const int g = t >> 9;
  const int mt = g % MT;
  const int s = g / MT;
  const int icb = s / 9, tap = s - icb * 9;
  const int kh = tap / 3, kw = tap - kh * 3;
  const int m = mt * 16 + (lane & 15);
  const int ic = icb * 32 + ((lane >> 4) << 3) + j;
  const float v = w[((m * CIN + ic) * 3 + kh) * 3 + kw];
  const unsigned short h = bf16rn(v);
  hi[t] = (short)h;
  lo[t] = (short)bf16rn(v - __uint_as_float((unsigned)h << 16));
}

template<int CIN, int COUT>
__device__ inline void wprep_dec_body(int t, const float* __restrict__ w,
                                      short* __restrict__ hi) {
  constexpr int MT = COUT / 16, ICB = CIN / 32;
  const int j = t & 7;
  const int lane = (t >> 3) & 63;
  const int g = t >> 9;
  const int mt = g % MT;
  const int u = g / MT;
  const int icb = u % ICB;
  const int e = u / ICB;
  const int ky = DKY[e], kx = DKX[e];
  const int m = mt * 16 + (lane & 15);
  const int ic = icb * 32 + ((lane >> 4) << 3) + j;
  hi[t] = (short)bf16rn(w[((ic * COUT + m) * 3 + ky) * 3 + kx]);
}

__global__ __launch_bounds__(256) void prep_all(
    const float* __restrict__ w2, const float* __restrict__ w3,
    const float* __restrict__ w4, const float* __restrict__ dw1,
    const float* __restrict__ dw2, const float* __restrict__ emb,
    short* __restrict__ a2h, short* __restrict__ a2l,
    short* __restrict__ a3h, short* __restrict__ a3l,
    short* __restrict__ a4h, short* __restrict__ a4l,
    short* __restrict__ ad1h, short* __restrict__ ad2h,
    float* __restrict__ nrm, short* __restrict__ ebh,
    short* __restrict__ ebl) {
  const int bb = blockIdx.x;
  const int tid = threadIdx.x;
  if (bb < 72) {
    wprep_conv_body<32, 64>(bb * 256 + tid, w2, a2h, a2l);
  } else if (bb < 360) {
    wprep_conv_body<64, 128>((bb - 72) * 256 + tid, w3, a3h, a3l);
  } else if (bb < 936) {
    wprep_conv_body<128, 128>((bb - 360) * 256 + tid, w4, a4h, a4l);
  } else if (bb < 1224) {
    wprep_dec_body<128, 64>((bb - 936) * 256 + tid, dw1, ad1h);
  } else if (bb < 1296) {
    wprep_dec_body<64, 32>((bb - 1224) * 256 + tid, dw2, ad2h);
  } else if (bb < 1424) {
    const int t = (bb - 1296) * 256 + tid;   // < 32768
    const int j  = t & 7;
    const int l  = (t >> 3) & 63;
    const int kk = (t >> 9) & 1;
    const int ct = t >> 10;
    const int code = ct * 16 + (l & 15);
    const int k = kk * 32 + ((l >> 4) << 3) + j;
    const float v = emb[code * 64 + k];
    const unsigned short h = bf16rn(v);
    ebh[t] = (short)h;
    ebl[t] = (short)bf16rn(v - __uint_as_float((unsigned)h << 16));
  } else {
    const int jj = (bb - 1424) * 256 + tid;
    if (jj < 512) {
      float s = 0.f;
      const float* e = emb + jj * 64;
#pragma unroll
      for (int k = 0; k < 64; ++k) s = fmaf(e[k], e[k], s);
      nrm[jj] = s;
    }
  }
}

// ------- generic strided conv MFMA (split xt -> split xt), NP tiles -------
// R23 (kept): A staged 2 tap-slices per buffer via direct global_load_lds,
// issued at top of super-tap; one barrier per 2 taps.
template<int CIN, int COUT, int OH, int OW, int S, int PHI, int PWI, int PHO, int PWO, int NP>
__global__ __launch_bounds__(256) void conv_mfma_xt(
    const short* __restrict__ xih, const short* __restrict__ xil,
    const short* __restrict__ ah,  const short* __restrict__ al,
    const float* __restrict__ bias,
    short* __restrict__ xoh, short* __restrict__ xol) {
  constexpr int MT = COUT / 16, ICB = CIN / 32;
  constexpr int PXB = 64 * NP, TPB = OH * OW / PXB;
  constexpr int NSL = ICB * 9;            // total A slices
  constexpr int NST = (NSL + 1) / 2;      // super-taps (2 slices each)
  constexpr int CH  = MT * 64;            // short8 chunks per slice
  constexpr int C2  = 2 * CH;             // chunks per buffer
  constexpr int CPT = (C2 + 255) / 256;   // chunks per thread
  __shared__ short ash[2][C2 * 8];
  __shared__ short asl2[2][C2 * 8];
  const int b = blockIdx.x;
  const int n = b / TPB, pt = b % TPB;
  const int tid = threadIdx.x;
  const int lane = tid & 63, wave = tid >> 6;
  const int quad = lane >> 4;
  int rr[NP], cc[NP];
  size_t bbase[NP];
#pragma unroll
  for (int p = 0; p < NP; ++p) {
    const int pl = pt * PXB + wave * (16 * NP) + p * 16 + (lane & 15);
    rr[p] = pl / OW; cc[p] = pl % OW;
    bbase[p] = (((size_t)n * PHI + S * rr[p]) * PWI + S * cc[p]) * CIN + quad * 8;
  }

  floatx4 acc[MT][NP];
#pragma unroll
  for (int mt = 0; mt < MT; ++mt)
#pragma unroll
    for (int p = 0; p < NP; ++p) acc[mt][p] = (floatx4){0.f, 0.f, 0.f, 0.f};

  // prologue: async-stage slices 0..1 into buffer 0
#pragma unroll
  for (int c = 0; c < CPT; ++c) {
    const int idx = tid + c * 256;
    if (idx < C2 && idx < NSL * CH) {
      gl_lds16(ah + (size_t)idx * 8, ash[0] + idx * 8);
      gl_lds16(al + (size_t)idx * 8, asl2[0] + idx * 8);
    }
  }
  __syncthreads();

  for (int st = 0; st < NST; ++st) {
    // issue next super-tap's slices directly into the inactive buffer
    if (st + 1 < NST) {
      const int base = (st + 1) * C2;
      const int nb = (st + 1) & 1;
#pragma unroll
      for (int c = 0; c < CPT; ++c) {
        const int idx = tid + c * 256;
        if (idx < C2 && base + idx < NSL * CH) {
          gl_lds16(ah + (size_t)(base + idx) * 8, ash[nb] + idx * 8);
          gl_lds16(al + (size_t)(base + idx) * 8, asl2[nb] + idx * 8);
        }
      }
    }
#pragma unroll
    for (int t2 = 0; t2 < 2; ++t2) {
      const int s = st * 2 + t2;
      if (s < NSL) {
        const int icb = s / 9, tap = s - icb * 9;
        const int kh = tap / 3, kw = tap - kh * 3;
        short8 bh[NP], bl[NP];
#pragma unroll
        for (int p = 0; p < NP; ++p) {
          const size_t be = bbase[p] + (size_t)(kh * PWI + kw) * CIN + icb * 32;
          bh[p] = *(const short8*)(xih + be);
          bl[p] = *(const short8*)(xil + be);
        }
        const short8* __restrict__ a8h = (const short8*)ash[st & 1] + t2 * CH;
        const short8* __restrict__ a8l = (const short8*)asl2[st & 1] + t2 * CH;
#pragma unroll
        for (int mt = 0; mt < MT; ++mt) {
          const short8 wh = a8h[mt * 64 + lane];
          const short8 wl = a8l[mt * 64 + lane];
#pragma unroll
          for (int p = 0; p < NP; ++p) {
            acc[mt][p] = __builtin_amdgcn_mfma_f32_16x16x32_bf16(wh, bh[p], acc[mt][p], 0, 0, 0);
            acc[mt][p] = __builtin_amdgcn_mfma_f32_16x16x32_bf16(wh, bl[p], acc[mt][p], 0, 0, 0);
            acc[mt][p] = __builtin_amdgcn_mfma_f32_16x16x32_bf16(wl, bh[p], acc[mt][p], 0, 0, 0);
          }
        }
      }
    }
    if (st + 1 < NST) __syncthreads();
  }
#pragma unroll
  for (int p = 0; p < NP; ++p) {
    const size_t ob = (((size_t)n * PHO + rr[p] + 1) * PWO + (cc[p] + 1)) * COUT + quad * 4;
#pragma unroll
    for (int mt = 0; mt < MT; ++mt) {
      short4v sh, sl;
#pragma unroll
      for (int q = 0; q < 4; ++q) {
        const float v = fmaxf(acc[mt][p][q] + bias[mt * 16 + quad * 4 + q], 0.f);
        const unsigned short hh = bf16rn(v);
        sh[q] = (short)hh;
        sl[q] = (short)bf16rn(v - __uint_as_float((unsigned)hh << 16));
      }
      *(short4v*)(xoh + ob + mt * 16) = sh;
      *(short4v*)(xol + ob + mt * 16) = sl;
    }
  }
}

// ---- fused transposed conv, plain bf16, NP pixel-tiles per wave ----------
// R15: ASTG=1 stages the per-icb A group (9 e-slices) in LDS, double-buffered.
template<int CIN, int COUT, int IH, int IW, int PHI, int PWI, int PHO, int PWO, int NP, int ASTG>
__global__ __launch_bounds__(256) void deconv_bf16_xt(
    const short* __restrict__ xih, const short* __restrict__ ah,
    const float* __restrict__ bias, short* __restrict__ xoh) {
  constexpr int MT = COUT / 16, ICB = CIN / 32;
  constexpr int PXB = 64 * NP, TPB = IH * IW / PXB;
  constexpr int CHI = 9 * MT * 64;               // chunks per icb A-group
  constexpr int CPT = (CHI + 255) / 256;
  constexpr int PHE[9] = {0, 1, 1, 2, 2, 3, 3, 3, 3};
  constexpr int DE[9]  = {0, 0, 1, 0, 2, 0, 1, 2, 3};
  __shared__ short ash[ASTG ? 2 * CHI * 8 : 1];
  const int b = blockIdx.x;
  const int n = b / TPB, pt = b % TPB;
  const int tid = threadIdx.x;
  const int lane = tid & 63, wave = tid >> 6;
  const int quad = lane >> 4;
  int ii[NP], jj[NP];
  size_t p00[NP];
#pragma unroll
  for (int p = 0; p < NP; ++p) {
    const int pl = pt * PXB + wave * (16 * NP) + p * 16 + (lane & 15);
    ii[p] = pl / IW; jj[p] = pl % IW;
    p00[p] = (((size_t)n * PHI + (ii[p] + 1)) * PWI + (jj[p] + 1)) * CIN + quad * 8;
  }

  floatx4 acc[4][MT][NP];
#pragma unroll
  for (int ph = 0; ph < 4; ++ph)
#pragma unroll
    for (int mt = 0; mt < MT; ++mt)
#pragma unroll
      for (int p = 0; p < NP; ++p) acc[ph][mt][p] = (floatx4){0.f, 0.f, 0.f, 0.f};

  const short8* __restrict__ ah8 = (const short8*)ah;

  short8 ra[ASTG ? CPT : 1];
  if constexpr (ASTG) {
    // prologue: stage icb0's 9 e-slices into buffer 0
#pragma unroll
    for (int c = 0; c < CPT; ++c) {
      const int idx = tid + c * 256;
      if (idx < CHI) {
        const int e = idx / (MT * 64);
        const int rem = idx - e * (MT * 64);
        ra[c] = ah8[(e * ICB + 0) * (MT * 64) + rem];
      }
    }
#pragma unroll
    for (int c = 0; c < CPT; ++c) {
      const int idx = tid + c * 256;
      if (idx < CHI) *(short8*)(ash + idx * 8) = ra[c];
    }
    __syncthreads();
  }

  for (int icb = 0; icb < ICB; ++icb) {
    short8 bh[NP][4];
#pragma unroll
    for (int p = 0; p < NP; ++p)
#pragma unroll
      for (int d = 0; d < 4; ++d)
        bh[p][d] = *(const short8*)(xih + p00[p] +
                                    (size_t)((d >> 1) * PWI + (d & 1)) * CIN + icb * 32);
    if constexpr (ASTG) {
      if (icb + 1 < ICB) {
#pragma unroll
        for (int c = 0; c < CPT; ++c) {
          const int idx = tid + c * 256;
          if (idx < CHI) {
            const int e = idx / (MT * 64);
            const int rem = idx - e * (MT * 64);
            ra[c] = ah8[(e * ICB + icb + 1) * (MT * 64) + rem];
          }
        }
      }
    }
#pragma unroll
    for (int e = 0; e < 9; ++e) {
      const int ph = PHE[e], d = DE[e];
#pragma unroll
      for (int mt = 0; mt < MT; ++mt) {
        short8 wh;
        if constexpr (ASTG)
          wh = ((const short8*)(ash + (size_t)(icb & 1) * CHI * 8))[(e * MT + mt) * 64 + lane];
        else
          wh = ah8[((e * ICB + icb) * MT + mt) * 64 + lane];
#pragma unroll
        for (int p = 0; p < NP; ++p)
          acc[ph][mt][p] = __builtin_amdgcn_mfma_f32_16x16x32_bf16(
              wh, bh[p][d], acc[ph][mt][p], 0, 0, 0);
      }
    }
    if constexpr (ASTG) {
      if (icb + 1 < ICB) {
        const size_t nb = (size_t)((icb + 1) & 1) * CHI * 8;
#pragma unroll
        for (int c = 0; c < CPT; ++c) {
          const int idx = tid + c * 256;
          if (idx < CHI) *(short8*)(ash + nb + idx * 8) = ra[c];
        }
        __syncthreads();
      }
    }
  }
#pragma unroll
  for (int p = 0; p < NP; ++p)
#pragma unroll
    for (int ph = 0; ph < 4; ++ph) {
      const int oy = 2 * ii[p] + (ph >> 1), ox = 2 * jj[p] + (ph & 1);
      const size_t ob = (((size_t)n * PHO + oy + 1) * PWO + (ox + 1)) * COUT + quad * 4;
#pragma unroll
      for (int mt = 0; mt < MT; ++mt) {
        short4v sh;
#pragma unroll
        for (int q = 0; q < 4; ++q)
          sh[q] = (short)bf16rn(fmaxf(acc[ph][mt][p][q] + bias[mt * 16 + quad * 4 + q], 0.f));
        *(short4v*)(xoh + ob + mt * 16) = sh;
      }
    }
}

// ---------------- conv4 MFMA (R20/R21): reg-staged 2-tap A, 18 barriers ---
__global__ __launch_bounds__(256) void conv4_mfma(
    const short* __restrict__ xthi, const short* __restrict__ xtlo,
    const short* __restrict__ ahi,  const short* __restrict__ alo,
    const float* __restrict__ bias,
    short* __restrict__ ench, short* __restrict__ encl) {
  __shared__ short ash[2][8192];        // 2 x 16384 B (A hi, two tap slices)
  __shared__ short asl[2][8192];        // 2 x 16384 B (A lo)
  const int b    = blockIdx.x;          // N*8 blocks, 128 pixels each
  const int n    = b >> 3;
  const int pt   = b & 7;
  const int tid  = threadIdx.x;
  const int lane = tid & 63;
  const int wave = tid >> 6;
  const int kq   = lane >> 4;
  int pl[2];
  size_t bbase[2];
#pragma unroll
  for (int p = 0; p < 2; ++p) {
    pl[p] = pt * 128 + wave * 32 + p * 16 + (lane & 15);
    const int r = pl[p] >> 5, c = pl[p] & 31;
    bbase[p] = (((size_t)n * 34 + r) * 34 + c) * 128 + kq * 8;
  }

  floatx4 acc[8][2];
#pragma unroll
  for (int mt = 0; mt < 8; ++mt)
#pragma unroll
    for (int p = 0; p < 2; ++p) acc[mt][p] = (floatx4){0.f, 0.f, 0.f, 0.f};

  const short8* __restrict__ ah8 = (const short8*)ahi;
  const short8* __restrict__ al8 = (const short8*)alo;

  // A prologue: stage tap-slices 0,1 (1024 chunks each of hi/lo) into buf 0
  short8 rah[4], ral[4];
#pragma unroll
  for (int c = 0; c < 4; ++c) {
    rah[c] = ah8[tid + c * 256];
    ral[c] = al8[tid + c * 256];
  }
#pragma unroll
  for (int c = 0; c < 4; ++c) {
    *(short8*)(ash[0] + (tid + c * 256) * 8) = rah[c];
    *(short8*)(asl[0] + (tid + c * 256) * 8) = ral[c];
  }
  __syncthreads();

  for (int st = 0; st < 18; ++st) {
    // prefetch next super-tap's 2 A slices into regs
    if (st < 17) {
      const int nb = (st + 1) * 1024;
#pragma unroll
      for (int c = 0; c < 4; ++c) {
        rah[c] = ah8[nb + tid + c * 256];
        ral[c] = al8[nb + tid + c * 256];
      }
    }
#pragma unroll
    for (int t2 = 0; t2 < 2; ++t2) {
      const int s = st * 2 + t2;
      const int icb = s / 9, tap = s - icb * 9;
      const int kh = tap / 3, kw = tap - kh * 3;
      const short8* __restrict__ a8h = (const short8*)ash[st & 1] + t2 * 512;
      const short8* __restrict__ a8l = (const short8*)asl[st & 1] + t2 * 512;
      short8 bh[2], bl[2];
#pragma unroll
      for (int p = 0; p < 2; ++p) {
        const size_t be = bbase[p] + (size_t)(kh * 34 + kw) * 128 + icb * 32;
        bh[p] = *(const short8*)(xthi + be);
        bl[p] = *(const short8*)(xtlo + be);
      }
#pragma unroll
      for (int mt = 0; mt < 8; ++mt) {
        const short8 ah = a8h[mt * 64 + lane];
        const short8 al = a8l[mt * 64 + lane];
#pragma unroll
        for (int p = 0; p < 2; ++p) {
          acc[mt][p] = __builtin_amdgcn_mfma_f32_16x16x32_bf16(ah, bh[p], acc[mt][p], 0, 0, 0);
          acc[mt][p] = __builtin_amdgcn_mfma_f32_16x16x32_bf16(ah, bl[p], acc[mt][p], 0, 0, 0);
          acc[mt][p] = __builtin_amdgcn_mfma_f32_16x16x32_bf16(al, bh[p], acc[mt][p], 0, 0, 0);
        }
      }
    }
    if (st < 17) {
      const int nbuf = (st + 1) & 1;
#pragma unroll
      for (int c = 0; c < 4; ++c) {
        *(short8*)(ash[nbuf] + (tid + c * 256) * 8) = rah[c];
        *(short8*)(asl[nbuf] + (tid + c * 256) * 8) = ral[c];
      }
      __syncthreads();
    }
  }
#pragma unroll
  for (int p = 0; p < 2; ++p) {
    const size_t obase = (size_t)n * 128 * 1024 + pl[p];
#pragma unroll
    for (int mt = 0; mt < 8; ++mt) {
#pragma unroll
      for (int q = 0; q < 4; ++q) {
        const int cout = mt * 16 + kq * 4 + q;
        const float rr = fmaxf(acc[mt][p][q] + bias[cout], 0.f);
        const unsigned short h = bf16rn(rr);
        const size_t oi = obase + (size_t)cout * 1024;
        ench[oi] = (short)h;
        encl[oi] = (short)bf16rn(rr - __uint_as_float((unsigned)h << 16));
      }
    }
  }
}

// ---- vq_mfma (R14): block = (n, one 64-px block, all 128 ch) -------------
__global__ __launch_bounds__(256) void vq_mfma(
    const short* __restrict__ fhi, const short* __restrict__ flo,
    const short* __restrict__ ebh, const short* __restrict__ ebl,
    const float* __restrict__ nrm, const float* __restrict__ emb,
    short* __restrict__ d1h) {
  __shared__ int sidx[128];
  const int lane = threadIdx.x & 63;
  const int wave = threadIdx.x >> 6;
  const int n  = blockIdx.x >> 4;
  const int pb = blockIdx.x & 15;

  short8 ah0[2], ah1[2], al0[2], al1[2];
#pragma unroll
  for (int g = 0; g < 2; ++g) {
    const int ch = wave * 32 + g * 16 + (lane & 15);
    const size_t abase = (((size_t)(n * 128 + ch)) * 16 + pb) * 64 + ((lane >> 4) << 3);
    ah0[g] = *(const short8*)(fhi + abase);
    ah1[g] = *(const short8*)(fhi + abase + 32);
    al0[g] = *(const short8*)(flo + abase);
    al1[g] = *(const short8*)(flo + abase + 32);
  }

  float bestv[2][4];
  int   besti[2][4];
#pragma unroll
  for (int g = 0; g < 2; ++g)
#pragma unroll
    for (int q = 0; q < 4; ++q) { bestv[g][q] = 3.4e38f; besti[g][q] = 0; }

  const short8* __restrict__ ebh8 = (const short8*)ebh;
  const short8* __restrict__ ebl8 = (const short8*)ebl;
  for (int ct = 0; ct < 32; ++ct) {
    const int f0 = (ct * 2) * 64 + lane;
    const short8 b0h = ebh8[f0];
    const short8 b1h = ebh8[f0 + 64];
    const short8 b0l = ebl8[f0];
    const short8 b1l = ebl8[f0 + 64];
    const int code = ct * 16 + (lane & 15);
    const float nn = nrm[code];
#pragma unroll
    for (int g = 0; g < 2; ++g) {
      floatx4 acc = {0.f, 0.f, 0.f, 0.f};
      acc = __builtin_amdgcn_mfma_f32_16x16x32_bf16(ah0[g], b0h, acc, 0, 0, 0);
      acc = __builtin_amdgcn_mfma_f32_16x16x32_bf16(ah1[g], b1h, acc, 0, 0, 0);
      acc = __builtin_amdgcn_mfma_f32_16x16x32_bf16(ah0[g], b0l, acc, 0, 0, 0);
      acc = __builtin_amdgcn_mfma_f32_16x16x32_bf16(ah1[g], b1l, acc, 0, 0, 0);
      acc = __builtin_amdgcn_mfma_f32_16x16x32_bf16(al0[g], b0h, acc, 0, 0, 0);
      acc = __builtin_amdgcn_mfma_f32_16x16x32_bf16(al1[g], b1h, acc, 0, 0, 0);
#pragma unroll
      for (int q = 0; q < 4; ++q) {
        const float sc = nn - 2.f * acc[q];
        if (sc < bestv[g][q]) { bestv[g][q] = sc; besti[g][q] = code; }
      }
    }
  }
#pragma unroll
  for (int off = 1; off < 16; off <<= 1) {
#pragma unroll
    for (int g = 0; g < 2; ++g)
#pragma unroll
      for (int q = 0; q < 4; ++q) {
        const float ov = __shfl_xor(bestv[g][q], off, 64);
        const int   oi = __shfl_xor(besti[g][q], off, 64);
        if (ov < bestv[g][q] || (ov == bestv[g][q] && oi < besti[g][q])) {
          bestv[g][q] = ov; besti[g][q] = oi;
        }
      }
  }
  if ((lane & 15) == 0) {
#pragma unroll
    for (int g = 0; g < 2; ++g)
#pragma unroll
      for (int q = 0; q < 4; ++q)
        sidx[wave * 32 + g * 16 + (lane >> 4) * 4 + q] = besti[g][q];
  }
  __syncthreads();
  const int chg = (threadIdx.x & 15) * 8;
  int gi8[8];
#pragma unroll
  for (int k = 0; k < 8; ++k) gi8[k] = sidx[chg + k];
#pragma unroll
  for (int pxg = 0; pxg < 4; ++pxg) {
    const int p = pxg * 16 + (threadIdx.x >> 4);   // 0..63
    const int pix = pb * 64 + p;
    const int r = pix >> 5, c = pix & 31;
    short8 v;
#pragma unroll
    for (int k = 0; k < 8; ++k)
      v[k] = (short)bf16rn(emb[(size_t)gi8[k] * 64 + p]);
    *(short8*)(d1h + (((size_t)n * 34 + r + 1) * 34 + (c + 1)) * 128 + chg) = v;
  }
}

// ---------------- dec3: fp32 direct from single-bf16 xt input -------------
__global__ __launch_bounds__(256) void dec3_xt(const short* __restrict__ xh,
                                               const float* __restrict__ w,
                                               const float* __restrict__ bias,
                                               float* __restrict__ out, int NH) {
  int t = blockIdx.x * 256 + threadIdx.x;
  if (t >= NH * 128 * 128) return;
  const int px = t & 16383;
  const int nl = t >> 14;
  const int i = px >> 7, j = px & 127;
  const float b0 = bias[0];
  float a00 = b0, a01 = b0, a10 = b0, a11 = b0;
  const size_t base00 = (((size_t)nl * 130 + i + 1) * 130 + (j + 1)) * 32;
#pragma unroll
  for (int icg = 0; icg < 4; ++icg) {
    const short8 h00 = *(const short8*)(xh + base00 + icg * 8);
    const short8 h01 = *(const short8*)(xh + base00 + 32 + icg * 8);
    const short8 h10 = *(const short8*)(xh + base00 + 130 * 32 + icg * 8);
    const short8 h11 = *(const short8*)(xh + base00 + 130 * 32 + 32 + icg * 8);
#pragma unroll
    for (int kk = 0; kk < 8; ++kk) {
      const int ic = icg * 8 + kk;
      const float x00 = bf2f1(h00[kk]);
      const float x01 = bf2f1(h01[kk]);
      const float x10 = bf2f1(h10[kk]);
      const float x11 = bf2f1(h11[kk]);
      const float* wp = w + ic * 9;
      a00 = fmaf(x00, wp[4], a00);
      a01 = fmaf(x00, wp[5], fmaf(x01, wp[3], a01));
      a10 = fmaf(x00, wp[7], fmaf(x10, wp[1], a10));
      a11 = fmaf(x00, wp[8], fmaf(x01, wp[6], fmaf(x10, wp[2], fmaf(x11, wp[0], a11))));
    }
  }
  float* op = out + ((size_t)nl * 256 + 2 * i) * 256 + 2 * j;
  op[0] = a00; op[1] = a01; op[256] = a10; op[257] = a11;
}

// ---------------------------------------------------------------------------
extern "C" void kernel_launch(void* const* d_in, const int* in_sizes, int n_in,
                              void* d_out, int out_size, void* d_ws, size_t ws_size,
                              hipStream_t stream) {
  const float* x   = (const float*)d_in[0];
  const float* w1  = (const float*)d_in[1];
  const float* b1  = (const float*)d_in[2];
  const float* w2  = (const float*)d_in[3];
  const float* b2  = (const float*)d_in[4];
  const float* w3  = (const float*)d_in[5];
  const float* b3  = (const float*)d_in[6];
  const float* w4  = (const float*)d_in[7];
  const float* b4  = (const float*)d_in[8];
  const float* emb = (const float*)d_in[9];
  const float* dw1 = (const float*)d_in[10];
  const float* db1 = (const float*)d_in[11];
  const float* dw2 = (const float*)d_in[12];
  const float* db2 = (const float*)d_in[13];
  const float* dw3 = (const float*)d_in[14];
  const float* db3 = (const float*)d_in[15];
  float* outp = (float*)d_out;

  const int N = in_sizes[0] / (2 * 256 * 256);  // 64
  if (N & 1) return;
  const int NH = N / 2;

  // ---- arena (units: floats; 1 float = 2 shorts); R7-proven footprint ----
  const size_t sx3 = (size_t)N * 66 * 66 * 64;
  const size_t sx2 = (size_t)NH * 130 * 130 * 32;
  const size_t sx4 = (size_t)N * 34 * 34 * 128;
  const size_t se  = (size_t)N * 128 * 1024;
  const size_t sd1 = sx4;
  const size_t smalls = 512 + 18432 + 73728 + 147456 + 73728 + 18432 + 32768;
  const size_t need = (sx3 + sx4 + se + sd1 + smalls) * sizeof(float);
  if (ws_size < need) return;

  float* ws = (float*)d_ws;
  short* x3h = (short*)ws;                 short* x3l = x3h + sx3;   // enc split
  short* x2h = (short*)(ws + sx3);         short* x2l = x2h + sx2;
  short* x4h = (short*)(ws + sx3);         short* x4l = x4h + sx4;
  short* ech = (short*)(ws + sx3 + sx4);   short* ecl = ech + se;
  short* d1h = (short*)(ws + sx3 + sx4 + se);   // bf16-only decoder bufs
  short* d2h = (short*)ws;
  short* d3h = (short*)(ws + sx3);
  float* sm  = ws + sx3 + sx4 + se + sd1;
  float* nrm = sm;
  short* a2h = (short*)(sm + 512);                         short* a2l = a2h + 18432;
  short* a3h = (short*)(sm + 512 + 18432);                 short* a3l = a3h + 73728;
  short* a4h = (short*)(sm + 512 + 18432 + 73728);         short* a4l = a4h + 147456;
  short* ad1h = (short*)(sm + 512 + 18432 + 73728 + 147456);           // hi only
  short* ad2h = (short*)(sm + 512 + 18432 + 73728 + 147456 + 73728);   // hi only
  short* ebh = (short*)(sm + 512 + 18432 + 73728 + 147456 + 73728 + 18432); short* ebl = ebh + 32768;

  // ---- fused weight preps + VQ tables (R15) ----
  prep_all<<<1426, 256, 0, stream>>>(w2, w3, w4, dw1, dw2, emb,
                                     a2h, a2l, a3h, a3l, a4h, a4l,
                                     ad1h, ad2h, nrm, ebh, ebl);

  // ---- encoder (split-bf16, NP=2; conv2/conv3 gl_lds, conv4 reg-staged) --
  ring_zero<<<(int)((NH * 516 * 32 + 255) / 256), 256, 0, stream>>>(x2h, x2l, NH, 130, 130, 32);
  ring_zero<<<(int)(((size_t)N * 260 * 64 + 255) / 256), 256, 0, stream>>>(x3h, x3l, N, 66, 66, 64);
  for (int half = 0; half < 2; ++half) {
    const int n0 = half * NH;
    conv1_xt<<<NH * 16384 / 256, 256, 0, stream>>>(
        x + (size_t)n0 * 2 * 65536, w1, b1, x2h, x2l, NH);
    conv_mfma_xt<32, 64, 64, 64, 2, 130, 130, 66, 66, 2>
        <<<NH * 32, 256, 0, stream>>>(x2h, x2l, a2h, a2l, b2,
                                      x3h + (size_t)n0 * 66 * 66 * 64,
                                      x3l + (size_t)n0 * 66 * 66 * 64);
  }
  ring_zero<<<(int)(((size_t)N * 132 * 128 + 255) / 256), 256, 0, stream>>>(x4h, x4l, N, 34, 34, 128);
  conv_mfma_xt<64, 128, 32, 32, 2, 66, 66, 34, 34, 2>
      <<<N * 8, 256, 0, stream>>>(x3h, x3l, a3h, a3l, b3, x4h, x4l);
  conv4_mfma<<<N * 8, 256, 0, stream>>>(x4h, x4l, a4h, a4l, b4, ech, ecl);

  // ---- VQ (split scoring, bf16 gather; R14 coalesced) ----
  ring_zero1<<<(int)(((size_t)N * 132 * 128 + 255) / 256), 256, 0, stream>>>(d1h, N, 34, 34, 128);
  vq_mfma<<<N * 16, 256, 0, stream>>>(ech, ecl, ebh, ebl, nrm, emb, d1h);

  // ---- decoder (plain bf16, NP=2; deconv1 A-LDS staged) ----
  ring_zero1<<<(int)(((size_t)N * 260 * 64 + 255) / 256), 256, 0, stream>>>(d2h, N, 66, 66, 64);
  deconv_bf16_xt<128, 64, 32, 32, 34, 34, 66, 66, 2, 1>
      <<<N * 8, 256, 0, stream>>>(d1h, ad1h, db1, d2h);
  ring_zero1<<<(int)((NH * 516 * 32 + 255) / 256), 256, 0, stream>>>(d3h, NH, 130, 130, 32);
  for (int half = 0; half < 2; ++half) {
    const int n0 = half * NH;
    deconv_bf16_xt<64, 32, 64, 64, 66, 66, 130, 130, 2, 0>
        <<<NH * 32, 256, 0, stream>>>(d2h + (size_t)n0 * 66 * 66 * 64,
                                      ad2h, db2, d3h);
    dec3_xt<<<NH * 16384 / 256, 256, 0, stream>>>(
        d3h, dw3, db3, outp + (size_t)n0 * 65536, NH);
  }
}